// Round 23
// baseline (541.750 us; speedup 1.0000x reference)
//
#include <hip/hip_runtime.h>

typedef unsigned short u16;
typedef unsigned int u32;
typedef float f32x4 __attribute__((ext_vector_type(4)));
typedef short bf16x8 __attribute__((ext_vector_type(8)));
typedef short s16x4 __attribute__((ext_vector_type(4)));

// ---- geometry ----
// B=512, DIM=384, RES=7, N=49, NH=8, KD=32, D=128, DH=1024, NHKD=256, HID=1536
// max-scalar table: mx[16 slots][64 regs]; readers take max over slots.
// regs: 0 Mq 1 Mk 2 Mv 3 Mvl 4 Mpre_th1 5 Mattn 6 Mpostsm 7 Mres_abs 8 Mres_pos
// 9 Mproj 10 Mx1 11 Mh1(relu) 12 Mmid(relu) 13 Mfc2 14 Mfinal

__device__ __forceinline__ u16 f2bf(float f){
  u32 x = __float_as_uint(f);
  x += 0x7fffu + ((x >> 16) & 1u);
  return (u16)(x >> 16);
}
__device__ __forceinline__ float bf2f(u16 u){ return __uint_as_float(((u32)u) << 16); }
__device__ __forceinline__ float qsc(float m, float qmax){ return fmaxf(m / qmax, 1e-8f); }
// exact-division fake quant (residual spine)
__device__ __forceinline__ float fq(float x, float s){
  return fminf(fmaxf(rintf(x / s), -127.f), 127.f) * s;
}
// reciprocal-mul fake quant (ls1/ls2-insulated paths)
__device__ __forceinline__ float fqi(float x, float s, float inv){
  return fminf(fmaxf(rintf(x * inv), -127.f), 127.f) * s;
}
// read a scale reg: max over the 16 contention slots
__device__ __forceinline__ float rdmx(const float* mx, int reg){
  float m = mx[reg];
  #pragma unroll
  for (int s = 1; s < 16; ++s) m = fmaxf(m, mx[s*64 + reg]);
  return m;
}
// wave-shuffle block max -> slotted atomic (2 barriers)
__device__ __forceinline__ void blockMaxTo(float* mx, int reg, float v){
  __shared__ float red[8];
  #pragma unroll
  for (int o = 32; o > 0; o >>= 1) v = fmaxf(v, __shfl_xor(v, o, 64));
  const int wid = threadIdx.x >> 6;
  const int nw = (int)(blockDim.x + 63) >> 6;
  __syncthreads();
  if ((threadIdx.x & 63) == 0) red[wid] = v;
  __syncthreads();
  if (threadIdx.x == 0){
    float m = red[0];
    for (int i = 1; i < nw; ++i) m = fmaxf(m, red[i]);
    const int slot = (blockIdx.x + blockIdx.y*4) & 15;
    atomicMax((int*)&mx[slot*64 + reg], __float_as_int(m));
  }
}
// two maxima in one pass (one barrier pair)
__device__ __forceinline__ void blockMax2To(float* mx, int r0i, float v0, int r1i, float v1){
  __shared__ float r0[8], r1[8];
  #pragma unroll
  for (int o = 32; o > 0; o >>= 1){
    v0 = fmaxf(v0, __shfl_xor(v0, o, 64));
    v1 = fmaxf(v1, __shfl_xor(v1, o, 64));
  }
  const int wid = threadIdx.x >> 6;
  const int nw = (int)(blockDim.x + 63) >> 6;
  __syncthreads();
  if ((threadIdx.x & 63) == 0){ r0[wid] = v0; r1[wid] = v1; }
  __syncthreads();
  if (threadIdx.x == 0){
    float m0 = r0[0], m1 = r1[0];
    for (int i = 1; i < nw; ++i){ m0 = fmaxf(m0, r0[i]); m1 = fmaxf(m1, r1[i]); }
    const int slot = (blockIdx.x + blockIdx.y*4) & 15;
    atomicMax((int*)&mx[slot*64 + r0i], __float_as_int(m0));
    atomicMax((int*)&mx[slot*64 + r1i], __float_as_int(m1));
  }
}

__device__ __forceinline__ void gload16(const void* g, void* l){
  __builtin_amdgcn_global_load_lds((const __attribute__((address_space(1))) u32*)g,
                                   (__attribute__((address_space(3))) u32*)l, 16, 0, 0);
}

__global__ void zeromx(float* mx){
  for (int j = threadIdx.x; j < 1024; j += 256) mx[j] = 0.f;
}

// ---------------- weight quantization (per-output-channel) + biasx table ----------------
__global__ __launch_bounds__(128) void wquant(
    const float* wq, const float* wk, const float* wv, const float* wproj,
    const float* wfc1, const float* wfc2, const float* wvl, const float* wmid,
    const float* wth1, const float* wth2,
    const float* bq, const float* bk, const float* bv,
    const float* ab, const int* idxs,
    u16* wqkv_b, u16* wproj_b, u16* wfc1_b, u16* wfc2_b,
    float* wvl_q, float* wmid_q, float* wth1_q, float* wth2_q, float* biasqkv,
    float* biasx)
{
  const int tid = threadIdx.x;
  const int bid = blockIdx.x;
  if (bid == 6416){
    for (int j = tid; j < 1536; j += 128){
      float v = (j < 256) ? bq[j] : ((j < 512) ? bk[j - 256] : bv[j - 512]);
      biasqkv[j] = v;
    }
    return;
  }
  if (bid >= 6417){   // relative-position bias expanded per head: biasx[h][t]
    const int h = bid - 6417;
    for (int j = tid; j < 2401; j += 128)
      biasx[h*2401 + j] = ab[h*49 + idxs[j]];
    return;
  }
  const int rows[10] = {256,256,1024,384,1536,384,1024,1536,8,8};
  int seg = 0, r = bid;
  while (r >= rows[seg]) { r -= rows[seg]; ++seg; }
  int len = 0;
  const float* src = nullptr; u16* db = nullptr; float* df = nullptr;
  switch (seg){
    case 0: len = 384;  src = wq    + r*384;  db = wqkv_b + r*384;        break;
    case 1: len = 384;  src = wk    + r*384;  db = wqkv_b + (256+r)*384;  break;
    case 2: len = 384;  src = wv    + r*384;  db = wqkv_b + (512+r)*384;  break;
    case 3: len = 1024; src = wproj + r*1024; db = wproj_b + r*1024;      break;
    case 4: len = 384;  src = wfc1  + r*384;  db = wfc1_b + r*384;        break;
    case 5: len = 1536; src = wfc2  + r*1536; db = wfc2_b + r*1536;       break;
    case 6: len = 9;    src = wvl   + r*9;    df = wvl_q + r*9;           break;
    case 7: len = 9;    src = wmid  + r*9;    df = wmid_q + r*9;          break;
    case 8: len = 8;    src = wth1  + r*8;    df = wth1_q + r*8;          break;
    default: len = 8;   src = wth2  + r*8;    df = wth2_q + r*8;          break;
  }
  float lm = 0.f;
  for (int j = tid; j < len; j += 128) lm = fmaxf(lm, fabsf(src[j]));
  __shared__ float red[128];
  red[tid] = lm; __syncthreads();
  for (int s = 64; s > 0; s >>= 1){
    if (tid < s) red[tid] = fmaxf(red[tid], red[tid + s]);
    __syncthreads();
  }
  float s = fmaxf(red[0] / 127.f, 1e-8f);
  for (int j = tid; j < len; j += 128){
    float v = fminf(fmaxf(rintf(src[j] / s), -127.f), 127.f) * s;
    if (db) db[j] = f2bf(v); else df[j] = v;
  }
}

// ---------------- x (NCHW) -> xT [m=b*49+p][c] bf16 ----------------
__global__ __launch_bounds__(256) void xpose(const float* __restrict__ x, u16* __restrict__ xT){
  const int b = blockIdx.x;
  __shared__ u16 xb[18816];
  const int tid = threadIdx.x;
  for (int jj = tid; jj < 4704; jj += 256){
    const float4 v = *(const float4*)&x[(size_t)b*18816 + jj*4];
    xb[jj*4+0] = f2bf(v.x); xb[jj*4+1] = f2bf(v.y);
    xb[jj*4+2] = f2bf(v.z); xb[jj*4+3] = f2bf(v.w);
  }
  __syncthreads();
  for (int jj = tid; jj < 4704; jj += 256){
    int j = jj*4, p = j / 384, c = j - p*384;
    s16x4 o;
    #pragma unroll
    for (int u = 0; u < 4; ++u) o[u] = (short)xb[(c+u)*49 + p];
    *(s16x4*)&xT[(size_t)b*18816 + j] = o;
  }
}

// ---------------- bf16 MFMA GEMM: C[M][N] = A[M][K] * Bt[N][K]^T + bias ----------------
// R16/R18 known-good structure (2-barrier drain loop). Used for proj (aquant=1)
// and fc2 (aquant=2) — the reg-staged quant paths.
__global__ __launch_bounds__(256, 3) void gemm_bt(
    const u16* __restrict__ A, const u16* __restrict__ Bt,
    const float* __restrict__ bias, u16* __restrict__ C,
    float* __restrict__ mx, int N, int K, int epi, int region, int aquant)
{
  const int nx = gridDim.x;
  const int nwg = nx * gridDim.y;
  const int orig = blockIdx.x + nx * blockIdx.y;      // HW dispatch order (x fastest)
  const int q8 = nwg >> 3, r8 = nwg & 7;
  const int xcd = orig & 7;
  const int lid = ((xcd < r8) ? xcd*(q8+1) : r8*(q8+1) + (xcd - r8)*q8) + (orig >> 3);
  const int n0 = (lid % nx) * 128;
  const int m0 = (lid / nx) * 128;
  __shared__ __align__(16) u16 As[128*64];
  __shared__ __align__(16) u16 Bs[128*64];
  const int tid = threadIdx.x;
  const int lane = tid & 63, wid = tid >> 6;
  const int wr = wid >> 1, wc = wid & 1;
  float qa_s0 = 1.f, qa_i0 = 1.f, qa_s1 = 1.f, qa_i1 = 1.f;
  if (aquant == 1){
    qa_s0 = qsc(rdmx(mx,7), 127.f); qa_i0 = 1.f/qa_s0;
    float posq = fq(rdmx(mx,8), qa_s0);
    qa_s1 = fmaxf(posq / 127.f, 1e-8f); qa_i1 = 1.f/qa_s1;
  } else if (aquant == 2){
    qa_s0 = qsc(rdmx(mx,12), 127.f); qa_i0 = 1.f/qa_s0;
  }
  f32x4 acc[4][4] = {};
  const int nsteps = K >> 6;
  for (int s = 0; s < nsteps; ++s){
    const int k0 = s << 6;
    #pragma unroll
    for (int j = 0; j < 4; ++j){
      int boff = j*4096 + tid*16;      // LDS byte offset (wave-linear dest)
      int row = boff >> 7;
      // inverse-swizzled global source column (involution: read applies same XOR)
      int ce  = (((boff & 127) ^ ((row & 7) << 4)) >> 1);
      if (aquant == 0){
        gload16(A + (size_t)(m0 + row)*K + k0 + ce, (char*)As + boff);
      } else {
        uint4 va = *(const uint4*)(A + (size_t)(m0 + row)*K + k0 + ce);
        u16* e = (u16*)&va;
        #pragma unroll
        for (int u = 0; u < 8; ++u){
          float f = bf2f(e[u]);
          if (aquant == 1){
            f = fmaxf(fqi(f, qa_s0, qa_i0), 0.f);
            f = fqi(f, qa_s1, qa_i1);
          } else {
            f = fqi(f, qa_s0, qa_i0);
          }
          e[u] = f2bf(f);
        }
        *(uint4*)((char*)As + boff) = va;
      }
      gload16(Bt + (size_t)(n0 + row)*K + k0 + ce, (char*)Bs + boff);
    }
    __syncthreads();
    #pragma unroll
    for (int kk = 0; kk < 2; ++kk){
      bf16x8 af[4], bfr[4];
      #pragma unroll
      for (int i = 0; i < 4; ++i){
        int ar = wr*64 + i*16 + (lane & 15);
        int aidx = (ar*64 + kk*32 + (lane >> 4)*8) ^ ((ar & 7) << 3);
        af[i]  = *(const bf16x8*)&As[aidx];
        int br = wc*64 + i*16 + (lane & 15);
        int bidx = (br*64 + kk*32 + (lane >> 4)*8) ^ ((br & 7) << 3);
        bfr[i] = *(const bf16x8*)&Bs[bidx];
      }
      #pragma unroll
      for (int i = 0; i < 4; ++i){
        #pragma unroll
        for (int j = 0; j < 4; ++j){
          acc[i][j] = __builtin_amdgcn_mfma_f32_16x16x32_bf16(af[i], bfr[j], acc[i][j], 0, 0, 0);
        }
      }
    }
    __syncthreads();
  }
  float lm = 0.f;
  #pragma unroll
  for (int i = 0; i < 4; ++i){
    int rbase = m0 + wr*64 + i*16 + ((lane >> 4) << 2);
    #pragma unroll
    for (int j = 0; j < 4; ++j){
      int col = n0 + wc*64 + j*16 + (lane & 15);
      float bv = bias[col];
      #pragma unroll
      for (int q = 0; q < 4; ++q){
        float v = acc[i][j][q] + bv;
        if (epi == 2) v = fmaxf(v, 0.f);
        C[(size_t)(rbase + q)*N + col] = f2bf(v);
        lm = fmaxf(lm, (epi == 2) ? v : fabsf(v));
      }
    }
  }
  int reg = region;
  if (epi == 1) reg = (n0 < 256) ? 0 : ((n0 < 512) ? 1 : 2);
  blockMaxTo(mx, reg, lm);
}

// ------------- pipelined GEMM (aquant=0 only): BK=32 double-buffer, counted vmcnt ------
// Same 32 KB LDS as gemm_bt (As[2]+Bs[2] at 128x32 each) -> occupancy preserved.
// Next tile's 4 global_load_lds stay in flight across a RAW s_barrier (no vmcnt(0)
// drain — the m97-ceiling stall). RAW: vmcnt(4)+barrier; WAR: end-of-compute barrier
// (ds_reads retired before MFMA via compiler lgkmcnt). "memory" clobbers pin ordering.
// LDS swizzle for 64B rows: slot ^= (row>>1)&3 — 2 lanes/bank-granule (free, m136);
// staging source pre-applies the same involution. K-accumulation order identical to
// gemm_bt -> bit-identical results.
__global__ __launch_bounds__(256, 3) void gemm_p(
    const u16* __restrict__ A, const u16* __restrict__ Bt,
    const float* __restrict__ bias, u16* __restrict__ C,
    float* __restrict__ mx, int N, int K, int epi, int region)
{
  const int nx = gridDim.x;
  const int nwg = nx * gridDim.y;
  const int orig = blockIdx.x + nx * blockIdx.y;
  const int q8 = nwg >> 3, r8 = nwg & 7;
  const int xcd = orig & 7;
  const int lid = ((xcd < r8) ? xcd*(q8+1) : r8*(q8+1) + (xcd - r8)*q8) + (orig >> 3);
  const int n0 = (lid % nx) * 128;
  const int m0 = (lid / nx) * 128;
  __shared__ __align__(16) u16 As[2][128*32];
  __shared__ __align__(16) u16 Bs[2][128*32];
  const int tid = threadIdx.x;
  const int lane = tid & 63, wid = tid >> 6;
  const int wr = wid >> 1, wc = wid & 1;
  f32x4 acc[4][4] = {};
  const int nsteps = K >> 5;
  // per-thread staging geometry (2 rounds x 16B covers each 8 KB half)
  int srow[2], scol[2], sboff[2];
  #pragma unroll
  for (int r = 0; r < 2; ++r){
    int boff = r*4096 + tid*16;
    int row = boff >> 6;
    int slot = (boff >> 4) & 3;
    sboff[r] = boff;
    srow[r] = row;
    scol[r] = (slot ^ ((row >> 1) & 3)) << 3;   // inverse-swizzled source column
  }
  // prologue: stage tile 0 into buffer 0 (4 loads)
  #pragma unroll
  for (int r = 0; r < 2; ++r){
    gload16(A  + (size_t)(m0 + srow[r])*K + scol[r], (char*)As[0] + sboff[r]);
    gload16(Bt + (size_t)(n0 + srow[r])*K + scol[r], (char*)Bs[0] + sboff[r]);
  }
  for (int s = 0; s < nsteps; ++s){
    const int cur = s & 1;
    if (s + 1 < nsteps){
      const int k1 = (s + 1) << 5;
      #pragma unroll
      for (int r = 0; r < 2; ++r){
        gload16(A  + (size_t)(m0 + srow[r])*K + k1 + scol[r], (char*)As[cur ^ 1] + sboff[r]);
        gload16(Bt + (size_t)(n0 + srow[r])*K + k1 + scol[r], (char*)Bs[cur ^ 1] + sboff[r]);
      }
      asm volatile("s_waitcnt vmcnt(4)" ::: "memory");   // cur tile landed; next 4 in flight
    } else {
      asm volatile("s_waitcnt vmcnt(0)" ::: "memory");
    }
    asm volatile("s_barrier" ::: "memory");              // all waves' cur loads landed
    bf16x8 af[4], bfr[4];
    #pragma unroll
    for (int i = 0; i < 4; ++i){
      int ar = wr*64 + i*16 + (lane & 15);
      int ab2 = ar*64 + ((((lane >> 4) ^ ((ar >> 1) & 3))) << 4);
      af[i]  = *(const bf16x8*)((const char*)As[cur] + ab2);
      int br = wc*64 + i*16 + (lane & 15);
      int bb2 = br*64 + ((((lane >> 4) ^ ((br >> 1) & 3))) << 4);
      bfr[i] = *(const bf16x8*)((const char*)Bs[cur] + bb2);
    }
    #pragma unroll
    for (int i = 0; i < 4; ++i){
      #pragma unroll
      for (int j = 0; j < 4; ++j){
        acc[i][j] = __builtin_amdgcn_mfma_f32_16x16x32_bf16(af[i], bfr[j], acc[i][j], 0, 0, 0);
      }
    }
    asm volatile("s_barrier" ::: "memory");              // all waves done reading cur
  }
  float lm = 0.f;
  #pragma unroll
  for (int i = 0; i < 4; ++i){
    int rbase = m0 + wr*64 + i*16 + ((lane >> 4) << 2);
    #pragma unroll
    for (int j = 0; j < 4; ++j){
      int col = n0 + wc*64 + j*16 + (lane & 15);
      float bv = bias[col];
      #pragma unroll
      for (int q = 0; q < 4; ++q){
        float v = acc[i][j][q] + bv;
        if (epi == 2) v = fmaxf(v, 0.f);
        C[(size_t)(rbase + q)*N + col] = f2bf(v);
        lm = fmaxf(lm, (epi == 2) ? v : fabsf(v));
      }
    }
  }
  int reg = region;
  if (epi == 1) reg = (n0 < 256) ? 0 : ((n0 < 512) ? 1 : 2);
  blockMaxTo(mx, reg, lm);
}

// ---------------- S = q*k^T*scale + bias — MFMA, 4 batches/block ----------------
__global__ __launch_bounds__(256) void attn_qk(
    const u16* __restrict__ qkv, const float* __restrict__ biasx,
    const float* __restrict__ wv9, const float* __restrict__ bvl,
    u16* __restrict__ S, u16* __restrict__ vlb, float* __restrict__ mx)
{
  const int h = blockIdx.x;
  __shared__ __align__(16) float xin[6272];   // quantized V [p][c], stride 128
  __shared__ __align__(16) u16 Qb[64*40];     // [n][kd] int-valued bf16, stride 40
  __shared__ __align__(16) u16 Kb[64*40];     // [m][kd] int-valued bf16, stride 40
  const float sq = qsc(rdmx(mx,0), 127.f), sk = qsc(rdmx(mx,1), 127.f), sv = qsc(rdmx(mx,2), 127.f);
  const float iq = 1.f/sq, ik = 1.f/sk, iv = 1.f/sv;
  const int tid = threadIdx.x;
  const int lane = tid & 63, wid = tid >> 6;
  const int c = tid & 127, half = tid >> 7;
  float w9[9];
  #pragma unroll
  for (int t = 0; t < 9; ++t) w9[t] = wv9[h*1152 + c*9 + t];
  const float bb = bvl[h*128 + c];
  const float sscale = (sq * sk) * 0.17677669529663687f;
  const float* bx = biasx + h*2401;
  const int col = wid*16 + (lane & 15);
  float lm = 0.f, lmV = 0.f;
  for (int bb4 = 0; bb4 < 4; ++bb4){
    const int b = blockIdx.y*4 + bb4;
    __syncthreads();   // previous iteration's LDS readers done
    for (int j = tid; j < 196; j += 256){
      int n = j >> 2, d0 = (j & 3)*8;
      size_t base = (size_t)(b*49 + n)*1536;
      const bf16x8 qv = *(const bf16x8*)&qkv[base + h*32 + d0];
      const bf16x8 kv = *(const bf16x8*)&qkv[base + 256 + h*32 + d0];
      bf16x8 qo, ko;
      #pragma unroll
      for (int u = 0; u < 8; ++u){
        qo[u] = (short)f2bf(fminf(fmaxf(rintf(bf2f((u16)qv[u]) * iq), -127.f), 127.f));
        ko[u] = (short)f2bf(fminf(fmaxf(rintf(bf2f((u16)kv[u]) * ik), -127.f), 127.f));
      }
      *(bf16x8*)&Qb[n*40 + d0] = qo;
      *(bf16x8*)&Kb[n*40 + d0] = ko;
    }
    for (int j = tid; j < 784; j += 256){
      int p = j >> 4, dg = j & 15;
      const bf16x8 vv = *(const bf16x8*)&qkv[(size_t)(b*49 + p)*1536 + 512 + h*128 + dg*8];
      #pragma unroll
      for (int u = 0; u < 8; ++u)
        xin[p*128 + dg*8 + u] = fqi(bf2f((u16)vv[u]), sv, iv);
    }
    __syncthreads();
    // vl local branch: absmax + store pre-quant bf16
    {
      const int p0 = half*25, p1 = half ? 49 : 25;
      for (int p = p0; p < p1; ++p){
        const int py = p / 7, px = p - py*7;
        float acc = bb;
        #pragma unroll
        for (int dy = 0; dy < 3; ++dy){
          const int yy = py + dy - 1;
          if (yy < 0 || yy > 6) continue;
          #pragma unroll
          for (int dx = 0; dx < 3; ++dx){
            const int xx = px + dx - 1;
            if (xx < 0 || xx > 6) continue;
            acc += xin[(yy*7 + xx)*128 + c] * w9[dy*3 + dx];
          }
        }
        lmV = fmaxf(lmV, fabsf(acc));
        vlb[(size_t)(b*49 + p)*1024 + h*128 + c] = f2bf(acc);
      }
    }
    // MFMA: S(64x64) = Q(64x32) K^T(32x64)
    f32x4 acc[4] = {};
    {
      const bf16x8 bfr = *(const bf16x8*)&Kb[(wid*16 + (lane & 15))*40 + (lane >> 4)*8];
      #pragma unroll
      for (int i = 0; i < 4; ++i){
        const bf16x8 af = *(const bf16x8*)&Qb[(i*16 + (lane & 15))*40 + (lane >> 4)*8];
        acc[i] = __builtin_amdgcn_mfma_f32_16x16x32_bf16(af, bfr, acc[i], 0, 0, 0);
      }
    }
    if (col < 49){
      const size_t so = ((size_t)b*8 + h)*2401;
      #pragma unroll
      for (int i = 0; i < 4; ++i){
        #pragma unroll
        for (int q = 0; q < 4; ++q){
          const int row = i*16 + ((lane >> 4) << 2) + q;
          if (row < 49){
            float v = acc[i][q] * sscale + bx[row*49 + col];
            S[so + row*49 + col] = f2bf(v);
            lm = fmaxf(lm, fabsf(v));
          }
        }
      }
    }
  }
  blockMax2To(mx, 4, lm, 3, lmV);
}

// ---------------- talking head 1 (bf16, IN-PLACE on S; no restrict!) ----------------
__global__ __launch_bounds__(256) void th1k(
    const u16* S, const float* w1, const float* b1, u16* T, float* mx)
{
  const int b = blockIdx.y;
  const int j = blockIdx.x*256 + threadIdx.x;
  __shared__ float wsh[64];
  __shared__ float bsh[8];
  if (threadIdx.x < 64) wsh[threadIdx.x] = w1[threadIdx.x];
  if (threadIdx.x < 8)  bsh[threadIdx.x] = b1[threadIdx.x];
  __syncthreads();
  float lm = 0.f;
  if (j < 2401){
    const float s1 = qsc(rdmx(mx,4), 127.f);
    const float i1 = 1.f/s1;
    float a[8];
    #pragma unroll
    for (int h = 0; h < 8; ++h) a[h] = fqi(bf2f(S[((size_t)b*8 + h)*2401 + j]), s1, i1);
    float o8[8];
    #pragma unroll
    for (int o = 0; o < 8; ++o){
      float t = bsh[o];
      #pragma unroll
      for (int h = 0; h < 8; ++h) t += wsh[o*8 + h] * a[h];
      o8[o] = t;
      lm = fmaxf(lm, fabsf(t));
    }
    #pragma unroll
    for (int o = 0; o < 8; ++o) T[((size_t)b*8 + o)*2401 + j] = f2bf(o8[o]);
  }
  blockMaxTo(mx, 5, lm);
}

// ---------------- int softmax (I-BERT) + talking head 2 (bf16, IN-PLACE) --------------
__global__ __launch_bounds__(256) void smth2(
    const u16* T, const float* w2, const float* b2, u16* U, float* mx)
{
  const int b = blockIdx.x;
  __shared__ u16 P[19208];          // bf16 tile -> 4 blocks/CU
  __shared__ float wsh[64];
  __shared__ float bsh[8];
  const float sa = qsc(rdmx(mx,5), 127.f), ia = 1.f/sa;
  const int tid = threadIdx.x;
  if (tid < 64) wsh[tid] = w2[tid];
  if (tid < 8)  bsh[tid] = b2[tid];
  for (int j = tid; j < 19208; j += 256){
    float k = fminf(fmaxf(rintf(bf2f(T[(size_t)b*19208 + j]) * ia), -127.f), 127.f);
    P[j] = f2bf(k);                 // ints <=127: exact in bf16
  }
  __syncthreads();
  const float x0 = floorf(-0.6931f / sa);
  const float ix0 = 1.f / x0;
  const float bi = floorf((0.96963238f / 0.35815147f) / sa);
  const float ci = floorf((1.0f / 0.35815147f) / (sa * sa));
  const float Kc = ((0.35815147f * sa) * sa) * (1.f/1073741824.f);
  const float maxv = (ci * 1073741824.f) * Kc;    // analytic exp-tensor max
  const float se = fmaxf(maxv / 32767.f, 1e-8f);
  const float ise = 1.f / se;
  const float clampLo = 30.f * x0;
  for (int r = tid; r < 392; r += 256){
    u16* pr = &P[r*49];
    float rmax = -1e30f;
    for (int m = 0; m < 49; ++m) rmax = fmaxf(rmax, bf2f(pr[m]));
    float rsum = 0.f;
    for (int m = 0; m < 49; ++m){
      float xi = bf2f(pr[m]) - rmax;
      xi = fmaxf(xi, clampLo);
      float qd = floorf(xi * ix0);
      float rr = xi - x0*qd;
      float z = (rr + bi)*rr + ci;
      float ei = fmaxf(floorf(z * exp2f(30.f - qd)), 0.f);
      float e2 = fminf(fmaxf(rintf((ei * Kc) * ise), -32767.f), 32767.f);
      u16 eb = f2bf(e2);
      pr[m] = eb;
      rsum += bf2f(eb);
    }
    const float factor = floorf(4294967296.f / rsum);
    for (int m = 0; m < 49; ++m){
      float p = floorf((bf2f(pr[m]) * factor) * (1.f/65536.f)) * (1.f/65536.f);
      pr[m] = f2bf(p);
    }
  }
  __syncthreads();
  float lm = 0.f;
  for (int j = tid; j < 19208; j += 256){
    int o = j / 2401, rem = j - o*2401;
    float t = bsh[o];
    #pragma unroll
    for (int h = 0; h < 8; ++h) t += wsh[o*8 + h] * bf2f(P[h*2401 + rem]);
    U[(size_t)b*19208 + j] = f2bf(t);
    lm = fmaxf(lm, fabsf(t));
  }
  blockMaxTo(mx, 6, lm);
}

// ------ out = attn_q @ v_q + fq(vl) — MFMA; vl prefetched into REGISTERS ------------
__global__ __launch_bounds__(256) void attn_v(
    const u16* __restrict__ qkv, const u16* __restrict__ U,
    u16* __restrict__ av, float* __restrict__ mx)
{
  const int h = blockIdx.x, b = blockIdx.y;
  __shared__ __align__(16) u16 Pb[64*68];     // [n][k=m] int-valued bf16, stride 68
  __shared__ __align__(16) u16 Vt[128*66];    // [d][k=m] int-valued bf16, stride 66
  const float s3 = qsc(rdmx(mx,6), 127.f), sv = qsc(rdmx(mx,2), 127.f), svl = qsc(rdmx(mx,3), 127.f);
  const float i3 = 1.f/s3, iv = 1.f/sv, il = 1.f/svl;
  const float s3sv = s3 * sv;
  const int tid = threadIdx.x;
  const int lane = tid & 63, wid = tid >> 6;
  const int col0 = wid * 32;
  const int ca = col0 + (lane & 15), cb = ca + 16;   // the two columns this thread owns
  // prefetch vl (written by attn_qk into av) into registers, issued FIRST so the
  // HBM latency hides under P/V staging; consumed only in the epilogue.
  u16 vlrA[16], vlrB[16];
  {
    const size_t vbase = (size_t)(b*49)*1024 + h*128;
    #pragma unroll
    for (int i = 0; i < 4; ++i){
      #pragma unroll
      for (int q = 0; q < 4; ++q){
        const int row = i*16 + ((lane >> 4) << 2) + q;
        const int rr = (row < 49) ? row : 48;   // clamp (values unused for row>=49)
        vlrA[i*4+q] = av[vbase + (size_t)rr*1024 + ca];
        vlrB[i*4+q] = av[vbase + (size_t)rr*1024 + cb];
      }
    }
  }
  // zero k-pad columns only; rows >=49 of the MFMA output are discarded
  for (int j = tid; j < 64*19; j += 256){ int n = j/19, m = 49 + (j - n*19); Pb[n*68 + m] = 0; }
  for (int j = tid; j < 128*17; j += 256){ int d = j/17, m = 49 + (j - d*17); Vt[d*66 + m] = 0; }
  // P-quant: integer-valued bf16
  for (int j = tid; j < 2401; j += 256){
    int n = j / 49, m = j - n*49;
    float k = fminf(fmaxf(rintf(bf2f(U[((size_t)b*8 + h)*2401 + j]) * i3), -127.f), 127.f);
    Pb[n*68 + m] = f2bf(k);
  }
  // V-quant, d-major
  {
    const int dp = lane * 2, mc = wid;
    const int mend = (mc == 3) ? 49 : (mc*13 + 13);
    const size_t base = (size_t)(b*49)*1536 + 512 + h*128 + dp;
    for (int m = mc*13; m < mend; ++m){
      u32 two = *(const u32*)&qkv[base + (size_t)m*1536];
      float k0 = fminf(fmaxf(rintf(bf2f((u16)(two & 0xffffu)) * iv), -127.f), 127.f);
      float k1 = fminf(fmaxf(rintf(bf2f((u16)(two >> 16)) * iv), -127.f), 127.f);
      Vt[dp*66 + m]       = f2bf(k0);
      Vt[(dp + 1)*66 + m] = f2bf(k1);
    }
  }
  __syncthreads();
  // MFMA: P(64x64) x V^T(64x128) — per wave 64 rows x 32 cols
  f32x4 acc[4][2] = {};
  #pragma unroll
  for (int kk = 0; kk < 2; ++kk){
    bf16x8 af[4], bfr[2];
    #pragma unroll
    for (int i = 0; i < 4; ++i)
      af[i] = *(const bf16x8*)&Pb[(i*16 + (lane & 15))*68 + kk*32 + (lane >> 4)*8];
    #pragma unroll
    for (int j = 0; j < 2; ++j)
      bfr[j] = *(const bf16x8*)&Vt[(col0 + j*16 + (lane & 15))*66 + kk*32 + (lane >> 4)*8];
    #pragma unroll
    for (int i = 0; i < 4; ++i)
      #pragma unroll
      for (int j = 0; j < 2; ++j)
        acc[i][j] = __builtin_amdgcn_mfma_f32_16x16x32_bf16(af[i], bfr[j], acc[i][j], 0, 0, 0);
  }
  // epilogue: vl from registers, quantize, add, write
  float lm = 0.f, lmp = 0.f;
  #pragma unroll
  for (int i = 0; i < 4; ++i){
    #pragma unroll
    for (int q = 0; q < 4; ++q){
      const int row = i*16 + ((lane >> 4) << 2) + q;
      if (row < 49){
        const size_t base = (size_t)(b*49 + row)*1024 + h*128;
        const float vlA = fqi(bf2f(vlrA[i*4+q]), svl, il);
        const float vlB = fqi(bf2f(vlrB[i*4+q]), svl, il);
        const float vA = acc[i][0][q] * s3sv + vlA;
        const float vB = acc[i][1][q] * s3sv + vlB;
        av[base + ca] = f2bf(vA);
        av[base + cb] = f2bf(vB);
        lm = fmaxf(lm, fmaxf(fabsf(vA), fabsf(vB)));
        lmp = fmaxf(lmp, fmaxf(vA, vB));
      }
    }
  }
  blockMax2To(mx, 7, lm, 8, lmp);
}

// ---------------- y1 = x + ls1*quant(proj), absmax ----------------
__global__ __launch_bounds__(256) void res1max(
    const float* __restrict__ x, const u16* __restrict__ praw,
    const float* __restrict__ ls1, float* __restrict__ y1, float* __restrict__ mx)
{
  const int b = blockIdx.x;
  __shared__ float xs[18816];
  __shared__ float lss[384];
  const float sp = qsc(rdmx(mx,9), 127.f);
  const float ip = 1.f / sp;
  const int tid = threadIdx.x;
  for (int jj = tid; jj < 4704; jj += 256)
    *(float4*)&xs[jj*4] = *(const float4*)&x[(size_t)b*18816 + jj*4];
  for (int j = tid; j < 384; j += 256) lss[j] = ls1[j];
  __syncthreads();
  float lm = 0.f;
  for (int jj = tid; jj < 4704; jj += 256){
    int j = jj*4, p = j / 384, c = j - p*384;
    s16x4 pv = *(const s16x4*)&praw[(size_t)b*18816 + j];
    float4 yv;
    #pragma unroll
    for (int u = 0; u < 4; ++u){
      float y = xs[(c+u)*49 + p] + lss[c+u] * fqi(bf2f((u16)pv[u]), sp, ip);
      ((float*)&yv)[u] = y;
      lm = fmaxf(lm, fabsf(y));
    }
    *(float4*)&y1[(size_t)b*18816 + j] = yv;
  }
  blockMaxTo(mx, 10, lm);
}

// ---------------- x1 = quant(y1): bf16 only (values are 255-level quantized) ----------
__global__ void qx1(const float* __restrict__ y1, u16* __restrict__ x1b,
                    const float* __restrict__ mx){
  const float s = qsc(rdmx(mx,10), 127.f);
  const size_t n4 = (size_t)9633792/4;
  for (size_t i = (size_t)blockIdx.x*blockDim.x + threadIdx.x; i < n4; i += (size_t)gridDim.x*blockDim.x){
    float4 v = *(const float4*)(y1 + i*4);
    s16x4 ob;
    #pragma unroll
    for (int u = 0; u < 4; ++u){
      float q = fq(((const float*)&v)[u], s);   // spine: exact division
      ob[u] = (short)f2bf(q);
    }
    *(s16x4*)(x1b + i*4) = ob;
  }
}

// ---------------- depthwise 3x3 (mid conv) + relu (IN-PLACE on h1) ----------------
__global__ __launch_bounds__(128) void dw_mid(
    const u16* h1, const float* wm9, const float* bmid, u16* m1, float* mx)
{
  const int cc = blockIdx.x, b = blockIdx.y;
  __shared__ float xin[49*132];
  const float sh = qsc(rdmx(mx,11), 127.f);
  const float ih = 1.f / sh;
  const int tid = threadIdx.x;
  for (int j = tid; j < 784; j += 128){
    int p = j >> 4, dg = j & 15;
    const bf16x8 vv = *(const bf16x8*)&h1[(size_t)(b*49 + p)*1536 + cc*128 + dg*8];
    #pragma unroll
    for (int u = 0; u < 8; ++u)
      xin[p*132 + dg*8 + u] = fqi(bf2f((u16)vv[u]), sh, ih);
  }
  __syncthreads();
  const int c = tid;
  float w9[9];
  #pragma unroll
  for (int i = 0; i < 9; ++i) w9[i] = wm9[(cc*128 + c)*9 + i];
  const float bb = bmid[cc*128 + c];
  float col[49];
  #pragma unroll
  for (int p = 0; p < 49; ++p) col[p] = xin[p*132 + c];
  float lm = 0.f;
  #pragma unroll
  for (int p = 0; p < 49; ++p){
    const int py = p / 7, px = p % 7;
    float acc = bb;
    #pragma unroll
    for (int dy = 0; dy < 3; ++dy){
      const int yy = py + dy - 1;
      if (yy < 0 || yy > 6) continue;
      #pragma unroll
      for (int dx = 0; dx < 3; ++dx){
        const int xx = px + dx - 1;
        if (xx < 0 || xx > 6) continue;
        acc += col[yy*7 + xx] * w9[dy*3 + dx];
      }
    }
    acc = fmaxf(acc, 0.f);
    m1[(size_t)(b*49 + p)*1536 + cc*128 + c] = f2bf(acc);
    lm = fmaxf(lm, acc);
  }
  blockMaxTo(mx, 12, lm);
}

// ---------------- y2 = x1 + ls2*quant(fc2), absmax (bf16 in/out, x8) ----------------
__global__ __launch_bounds__(256) void res2max(
    const u16* __restrict__ x1b, const u16* __restrict__ f2,
    const float* __restrict__ ls2, u16* __restrict__ y2b, float* __restrict__ mx)
{
  const float s = qsc(rdmx(mx,13), 127.f);
  const float is = 1.f / s;
  float lm = 0.f;
  const size_t n8 = (size_t)9633792/8;
  for (size_t i = (size_t)blockIdx.x*blockDim.x + threadIdx.x; i < n8; i += (size_t)gridDim.x*blockDim.x){
    int c0 = (int)((i*8) % 384);
    bf16x8 xv = *(const bf16x8*)(x1b + i*8);
    bf16x8 fv = *(const bf16x8*)(f2 + i*8);
    bf16x8 yv;
    #pragma unroll
    for (int u = 0; u < 8; ++u){
      float y = bf2f((u16)xv[u]) + ls2[c0+u] * fqi(bf2f((u16)fv[u]), s, is);
      yv[u] = (short)f2bf(y);
      lm = fmaxf(lm, fabsf(y));
    }
    *(bf16x8*)(y2b + i*8) = yv;
  }
  blockMaxTo(mx, 14, lm);
}

// ---------------- out2 = quant(y2), transpose to NCHW, plus out_sf ----------------
__global__ __launch_bounds__(256) void finalout(
    const u16* __restrict__ y2b, float* __restrict__ out, const float* __restrict__ mx)
{
  const int b = blockIdx.x;
  __shared__ float os[18816];
  const float s = qsc(rdmx(mx,14), 127.f);
  const int tid = threadIdx.x;
  for (int jj = tid; jj < 4704; jj += 256){
    int j = jj*4, p = j / 384, c = j - p*384;
    s16x4 yv = *(const s16x4*)&y2b[(size_t)b*18816 + j];
    #pragma unroll
    for (int u = 0; u < 4; ++u)
      os[(c+u)*49 + p] = fq(bf2f((u16)yv[u]), s);   // spine: exact division
  }
  __syncthreads();
  for (int jj = tid; jj < 4704; jj += 256)
    *(float4*)&out[(size_t)b*18816 + jj*4] = *(const float4*)&os[jj*4];
  if (b == 0 && tid == 0) out[9633792] = s;
}

extern "C" void kernel_launch(void* const* d_in, const int* in_sizes, int n_in,
                              void* d_out, int out_size, void* d_ws, size_t ws_size,
                              hipStream_t stream)
{
  (void)in_sizes; (void)n_in; (void)out_size; (void)ws_size;
  const float* x    = (const float*)d_in[0];
  const float* wq   = (const float*)d_in[2];
  const float* bq   = (const float*)d_in[3];
  const float* wk   = (const float*)d_in[4];
  const float* bk   = (const float*)d_in[5];
  const float* wv   = (const float*)d_in[6];
  const float* bv   = (const float*)d_in[7];
  const float* wvl  = (const float*)d_in[8];
  const float* bvl  = (const float*)d_in[9];
  const float* ab   = (const float*)d_in[10];
  const float* wth1 = (const float*)d_in[11];
  const float* bth1 = (const float*)d_in[12];
  const float* wth2 = (const float*)d_in[13];
  const float* bth2 = (const float*)d_in[14];
  const float* wproj= (const float*)d_in[15];
  const float* bproj= (const float*)d_in[16];
  const float* wfc1 = (const float*)d_in[17];
  const float* bfc1 = (const float*)d_in[18];
  const float* wmid = (const float*)d_in[19];
  const float* bmid = (const float*)d_in[20];
  const float* wfc2 = (const float*)d_in[21];
  const float* bfc2 = (const float*)d_in[22];
  const float* ls1  = (const float*)d_in[23];
  const float* ls2  = (const float*)d_in[24];
  const int*   idxs = (const int*)d_in[25];
  float* out = (float*)d_out;

  // ---- workspace layout ----
  char* w = (char*)d_ws;
  float* biasqkv = (float*)(w + 256);
  u16* wqkv_b    = (u16*)(w + 6400);
  u16* wproj_b   = (u16*)(w + 1186048);
  u16* wfc1_b    = (u16*)(w + 1972480);
  u16* wfc2_b    = (u16*)(w + 3152128);
  float* wvl_q   = (float*)(w + 4331776);
  float* wmid_q  = (float*)(w + 4368640);
  float* wth1_q  = (float*)(w + 4423936);
  float* wth2_q  = (float*)(w + 4424192);
  // W1 (19.27 MB): xT -> praw -> x1b (alive qx1..res2max)
  u16* xT    = (u16*)(w + 4424448);
  u16* praw  = xT;
  u16* x1b   = xT;
  // W2 (77.07 MB): qkv -> h1 (dw_mid in place; fc2 reads h1 with A-quant)
  u16* qkv = (u16*)(w + 23692032);
  u16* h1  = qkv;
  // W4 (51.38 MB): avb — attn_qk stores pre-quant vl here; attn_v reads+overwrites;
  // proj gemm reads with A-quant
  u16* avb = (u16*)(w + 100762368);
  // W5 (39.34 MB): Sb bf16 (th1k/smth2 in place) -> y1 (f32) -> {f2raw, y2b} (bf16)
  u16* Sb   = (u16*)(w + 152142592);
  float* y1 = (float*)(w + 152142592);
  u16* f2raw = (u16*)(w + 152142592);             // after y1 dead (qx1 done)
  u16* y2b   = (u16*)(w + 152142592 + 19267584);  // disjoint from f2raw
  // biasx (76.8 KB) in the slack after W5
  float* biasx = (float*)(w + 190677760);
  // mx table: 16 slots x 64 regs (4 KB), after biasx
  float* mx = (float*)(w + 190754816);

  zeromx<<<1, 256, 0, stream>>>(mx);
  wquant<<<6425, 128, 0, stream>>>(wq, wk, wv, wproj, wfc1, wfc2, wvl, wmid, wth1, wth2,
                                   bq, bk, bv, ab, idxs,
                                   wqkv_b, wproj_b, wfc1_b, wfc2_b,
                                   wvl_q, wmid_q, wth1_q, wth2_q, biasqkv, biasx);
  xpose<<<512, 256, 0, stream>>>(x, xT);
  gemm_p<<<dim3(12, 196), 256, 0, stream>>>(xT, wqkv_b, biasqkv, qkv, mx, 1536, 384, 1, 0);
  attn_qk<<<dim3(8, 128), 256, 0, stream>>>(qkv, biasx, wvl_q, bvl, Sb, avb, mx);
  th1k<<<dim3(10, 512), 256, 0, stream>>>(Sb, wth1_q, bth1, Sb, mx);
  smth2<<<512, 256, 0, stream>>>(Sb, wth2_q, bth2, Sb, mx);
  attn_v<<<dim3(8, 512), 256, 0, stream>>>(qkv, Sb, avb, mx);
  gemm_bt<<<dim3(3, 196), 256, 0, stream>>>(avb, wproj_b, bproj, praw, mx, 384, 1024, 0, 9, 1);
  res1max<<<512, 256, 0, stream>>>(x, praw, ls1, y1, mx);
  qx1<<<2048, 256, 0, stream>>>(y1, x1b, mx);
  gemm_p<<<dim3(12, 196), 256, 0, stream>>>(x1b, wfc1_b, bfc1, h1, mx, 1536, 384, 2, 11);
  dw_mid<<<dim3(12, 512), 128, 0, stream>>>(h1, wmid_q, bmid, h1, mx);
  gemm_bt<<<dim3(3, 196), 256, 0, stream>>>(h1, wfc2_b, bfc2, f2raw, mx, 384, 1536, 0, 13, 2);
  res2max<<<2048, 256, 0, stream>>>(x1b, f2raw, ls2, y2b, mx);
  finalout<<<512, 256, 0, stream>>>(y2b, out, mx);
}

// Round 24
// 527.484 us; speedup vs baseline: 1.0270x; 1.0270x over previous
//
#include <hip/hip_runtime.h>

typedef unsigned short u16;
typedef unsigned int u32;
typedef float f32x4 __attribute__((ext_vector_type(4)));
typedef short bf16x8 __attribute__((ext_vector_type(8)));
typedef short s16x4 __attribute__((ext_vector_type(4)));

// ---- geometry ----
// B=512, DIM=384, RES=7, N=49, NH=8, KD=32, D=128, DH=1024, NHKD=256, HID=1536
// max-scalar table: mx[16 slots][64 regs]; readers take max over slots.
// regs: 0 Mq 1 Mk 2 Mv 3 Mvl 4 Mpre_th1 5 Mattn 6 Mpostsm 7 Mres_abs 8 Mres_pos
// 9 Mproj 10 Mx1 11 Mh1(relu) 12 Mmid(relu) 13 Mfc2 14 Mfinal

__device__ __forceinline__ u16 f2bf(float f){
  u32 x = __float_as_uint(f);
  x += 0x7fffu + ((x >> 16) & 1u);
  return (u16)(x >> 16);
}
__device__ __forceinline__ float bf2f(u16 u){ return __uint_as_float(((u32)u) << 16); }
__device__ __forceinline__ float qsc(float m, float qmax){ return fmaxf(m / qmax, 1e-8f); }
// exact-division fake quant (residual spine)
__device__ __forceinline__ float fq(float x, float s){
  return fminf(fmaxf(rintf(x / s), -127.f), 127.f) * s;
}
// reciprocal-mul fake quant (ls1/ls2-insulated paths)
__device__ __forceinline__ float fqi(float x, float s, float inv){
  return fminf(fmaxf(rintf(x * inv), -127.f), 127.f) * s;
}
// read a scale reg: max over the 16 contention slots
__device__ __forceinline__ float rdmx(const float* mx, int reg){
  float m = mx[reg];
  #pragma unroll
  for (int s = 1; s < 16; ++s) m = fmaxf(m, mx[s*64 + reg]);
  return m;
}
// wave-shuffle block max -> slotted atomic (2 barriers)
__device__ __forceinline__ void blockMaxTo(float* mx, int reg, float v){
  __shared__ float red[8];
  #pragma unroll
  for (int o = 32; o > 0; o >>= 1) v = fmaxf(v, __shfl_xor(v, o, 64));
  const int wid = threadIdx.x >> 6;
  const int nw = (int)(blockDim.x + 63) >> 6;
  __syncthreads();
  if ((threadIdx.x & 63) == 0) red[wid] = v;
  __syncthreads();
  if (threadIdx.x == 0){
    float m = red[0];
    for (int i = 1; i < nw; ++i) m = fmaxf(m, red[i]);
    const int slot = (blockIdx.x + blockIdx.y*4) & 15;
    atomicMax((int*)&mx[slot*64 + reg], __float_as_int(m));
  }
}
// two maxima in one pass (one barrier pair)
__device__ __forceinline__ void blockMax2To(float* mx, int r0i, float v0, int r1i, float v1){
  __shared__ float r0[8], r1[8];
  #pragma unroll
  for (int o = 32; o > 0; o >>= 1){
    v0 = fmaxf(v0, __shfl_xor(v0, o, 64));
    v1 = fmaxf(v1, __shfl_xor(v1, o, 64));
  }
  const int wid = threadIdx.x >> 6;
  const int nw = (int)(blockDim.x + 63) >> 6;
  __syncthreads();
  if ((threadIdx.x & 63) == 0){ r0[wid] = v0; r1[wid] = v1; }
  __syncthreads();
  if (threadIdx.x == 0){
    float m0 = r0[0], m1 = r1[0];
    for (int i = 1; i < nw; ++i){ m0 = fmaxf(m0, r0[i]); m1 = fmaxf(m1, r1[i]); }
    const int slot = (blockIdx.x + blockIdx.y*4) & 15;
    atomicMax((int*)&mx[slot*64 + r0i], __float_as_int(m0));
    atomicMax((int*)&mx[slot*64 + r1i], __float_as_int(m1));
  }
}

__device__ __forceinline__ void gload16(const void* g, void* l){
  __builtin_amdgcn_global_load_lds((const __attribute__((address_space(1))) u32*)g,
                                   (__attribute__((address_space(3))) u32*)l, 16, 0, 0);
}

__global__ void zeromx(float* mx){
  for (int j = threadIdx.x; j < 1024; j += 256) mx[j] = 0.f;
}

// ---------------- weight quantization (per-output-channel) + biasx table ----------------
__global__ __launch_bounds__(128) void wquant(
    const float* wq, const float* wk, const float* wv, const float* wproj,
    const float* wfc1, const float* wfc2, const float* wvl, const float* wmid,
    const float* wth1, const float* wth2,
    const float* bq, const float* bk, const float* bv,
    const float* ab, const int* idxs,
    u16* wqkv_b, u16* wproj_b, u16* wfc1_b, u16* wfc2_b,
    float* wvl_q, float* wmid_q, float* wth1_q, float* wth2_q, float* biasqkv,
    float* biasx)
{
  const int tid = threadIdx.x;
  const int bid = blockIdx.x;
  if (bid == 6416){
    for (int j = tid; j < 1536; j += 128){
      float v = (j < 256) ? bq[j] : ((j < 512) ? bk[j - 256] : bv[j - 512]);
      biasqkv[j] = v;
    }
    return;
  }
  if (bid >= 6417){   // relative-position bias expanded per head: biasx[h][t]
    const int h = bid - 6417;
    for (int j = tid; j < 2401; j += 128)
      biasx[h*2401 + j] = ab[h*49 + idxs[j]];
    return;
  }
  const int rows[10] = {256,256,1024,384,1536,384,1024,1536,8,8};
  int seg = 0, r = bid;
  while (r >= rows[seg]) { r -= rows[seg]; ++seg; }
  int len = 0;
  const float* src = nullptr; u16* db = nullptr; float* df = nullptr;
  switch (seg){
    case 0: len = 384;  src = wq    + r*384;  db = wqkv_b + r*384;        break;
    case 1: len = 384;  src = wk    + r*384;  db = wqkv_b + (256+r)*384;  break;
    case 2: len = 384;  src = wv    + r*384;  db = wqkv_b + (512+r)*384;  break;
    case 3: len = 1024; src = wproj + r*1024; db = wproj_b + r*1024;      break;
    case 4: len = 384;  src = wfc1  + r*384;  db = wfc1_b + r*384;        break;
    case 5: len = 1536; src = wfc2  + r*1536; db = wfc2_b + r*1536;       break;
    case 6: len = 9;    src = wvl   + r*9;    df = wvl_q + r*9;           break;
    case 7: len = 9;    src = wmid  + r*9;    df = wmid_q + r*9;          break;
    case 8: len = 8;    src = wth1  + r*8;    df = wth1_q + r*8;          break;
    default: len = 8;   src = wth2  + r*8;    df = wth2_q + r*8;          break;
  }
  float lm = 0.f;
  for (int j = tid; j < len; j += 128) lm = fmaxf(lm, fabsf(src[j]));
  __shared__ float red[128];
  red[tid] = lm; __syncthreads();
  for (int s = 64; s > 0; s >>= 1){
    if (tid < s) red[tid] = fmaxf(red[tid], red[tid + s]);
    __syncthreads();
  }
  float s = fmaxf(red[0] / 127.f, 1e-8f);
  for (int j = tid; j < len; j += 128){
    float v = fminf(fmaxf(rintf(src[j] / s), -127.f), 127.f) * s;
    if (db) db[j] = f2bf(v); else df[j] = v;
  }
}

// ---------------- x (NCHW) -> xT [m=b*49+p][c] bf16 ----------------
__global__ __launch_bounds__(256) void xpose(const float* __restrict__ x, u16* __restrict__ xT){
  const int b = blockIdx.x;
  __shared__ u16 xb[18816];
  const int tid = threadIdx.x;
  for (int jj = tid; jj < 4704; jj += 256){
    const float4 v = *(const float4*)&x[(size_t)b*18816 + jj*4];
    xb[jj*4+0] = f2bf(v.x); xb[jj*4+1] = f2bf(v.y);
    xb[jj*4+2] = f2bf(v.z); xb[jj*4+3] = f2bf(v.w);
  }
  __syncthreads();
  for (int jj = tid; jj < 4704; jj += 256){
    int j = jj*4, p = j / 384, c = j - p*384;
    s16x4 o;
    #pragma unroll
    for (int u = 0; u < 4; ++u) o[u] = (short)xb[(c+u)*49 + p];
    *(s16x4*)&xT[(size_t)b*18816 + j] = o;
  }
}

// ---------------- bf16 MFMA GEMM: C[M][N] = A[M][K] * Bt[N][K]^T + bias ----------------
// R16/R18 known-good structure + __launch_bounds__(256,3). SESSION-FINAL GEMM:
// T1 XCD-bijective remap + T2 st-16 XOR swizzle (conflicts=0), single-buffer
// 2-barrier loop (33 KB LDS, 64 VGPR). Escape attempts all measured dead ends:
// R17 dbuf (LDS x2 -> occupancy cliff), R19 BM=256 (VGPR cliff), R23 BK=32
// counted-vmcnt (neutral — cross-block overlap already hides the drain).
__global__ __launch_bounds__(256, 3) void gemm_bt(
    const u16* __restrict__ A, const u16* __restrict__ Bt,
    const float* __restrict__ bias, u16* __restrict__ C,
    float* __restrict__ mx, int N, int K, int epi, int region, int aquant)
{
  const int nx = gridDim.x;
  const int nwg = nx * gridDim.y;
  const int orig = blockIdx.x + nx * blockIdx.y;      // HW dispatch order (x fastest)
  const int q8 = nwg >> 3, r8 = nwg & 7;
  const int xcd = orig & 7;
  const int lid = ((xcd < r8) ? xcd*(q8+1) : r8*(q8+1) + (xcd - r8)*q8) + (orig >> 3);
  const int n0 = (lid % nx) * 128;
  const int m0 = (lid / nx) * 128;
  __shared__ __align__(16) u16 As[128*64];
  __shared__ __align__(16) u16 Bs[128*64];
  const int tid = threadIdx.x;
  const int lane = tid & 63, wid = tid >> 6;
  const int wr = wid >> 1, wc = wid & 1;
  float qa_s0 = 1.f, qa_i0 = 1.f, qa_s1 = 1.f, qa_i1 = 1.f;
  if (aquant == 1){
    qa_s0 = qsc(rdmx(mx,7), 127.f); qa_i0 = 1.f/qa_s0;
    float posq = fq(rdmx(mx,8), qa_s0);
    qa_s1 = fmaxf(posq / 127.f, 1e-8f); qa_i1 = 1.f/qa_s1;
  } else if (aquant == 2){
    qa_s0 = qsc(rdmx(mx,12), 127.f); qa_i0 = 1.f/qa_s0;
  }
  f32x4 acc[4][4] = {};
  const int nsteps = K >> 6;
  for (int s = 0; s < nsteps; ++s){
    const int k0 = s << 6;
    #pragma unroll
    for (int j = 0; j < 4; ++j){
      int boff = j*4096 + tid*16;      // LDS byte offset (wave-linear dest)
      int row = boff >> 7;
      // inverse-swizzled global source column (involution: read applies same XOR)
      int ce  = (((boff & 127) ^ ((row & 7) << 4)) >> 1);
      if (aquant == 0){
        gload16(A + (size_t)(m0 + row)*K + k0 + ce, (char*)As + boff);
      } else {
        uint4 va = *(const uint4*)(A + (size_t)(m0 + row)*K + k0 + ce);
        u16* e = (u16*)&va;
        #pragma unroll
        for (int u = 0; u < 8; ++u){
          float f = bf2f(e[u]);
          if (aquant == 1){
            f = fmaxf(fqi(f, qa_s0, qa_i0), 0.f);
            f = fqi(f, qa_s1, qa_i1);
          } else {
            f = fqi(f, qa_s0, qa_i0);
          }
          e[u] = f2bf(f);
        }
        *(uint4*)((char*)As + boff) = va;
      }
      gload16(Bt + (size_t)(n0 + row)*K + k0 + ce, (char*)Bs + boff);
    }
    __syncthreads();
    #pragma unroll
    for (int kk = 0; kk < 2; ++kk){
      bf16x8 af[4], bfr[4];
      #pragma unroll
      for (int i = 0; i < 4; ++i){
        int ar = wr*64 + i*16 + (lane & 15);
        int aidx = (ar*64 + kk*32 + (lane >> 4)*8) ^ ((ar & 7) << 3);
        af[i]  = *(const bf16x8*)&As[aidx];
        int br = wc*64 + i*16 + (lane & 15);
        int bidx = (br*64 + kk*32 + (lane >> 4)*8) ^ ((br & 7) << 3);
        bfr[i] = *(const bf16x8*)&Bs[bidx];
      }
      #pragma unroll
      for (int i = 0; i < 4; ++i){
        #pragma unroll
        for (int j = 0; j < 4; ++j){
          acc[i][j] = __builtin_amdgcn_mfma_f32_16x16x32_bf16(af[i], bfr[j], acc[i][j], 0, 0, 0);
        }
      }
    }
    __syncthreads();
  }
  float lm = 0.f;
  #pragma unroll
  for (int i = 0; i < 4; ++i){
    int rbase = m0 + wr*64 + i*16 + ((lane >> 4) << 2);
    #pragma unroll
    for (int j = 0; j < 4; ++j){
      int col = n0 + wc*64 + j*16 + (lane & 15);
      float bv = bias[col];
      #pragma unroll
      for (int q = 0; q < 4; ++q){
        float v = acc[i][j][q] + bv;
        if (epi == 2) v = fmaxf(v, 0.f);
        C[(size_t)(rbase + q)*N + col] = f2bf(v);
        lm = fmaxf(lm, (epi == 2) ? v : fabsf(v));
      }
    }
  }
  int reg = region;
  if (epi == 1) reg = (n0 < 256) ? 0 : ((n0 < 512) ? 1 : 2);
  blockMaxTo(mx, reg, lm);
}

// ---------------- S = q*k^T*scale + bias — MFMA, 4 batches/block ----------------
__global__ __launch_bounds__(256) void attn_qk(
    const u16* __restrict__ qkv, const float* __restrict__ biasx,
    const float* __restrict__ wv9, const float* __restrict__ bvl,
    u16* __restrict__ S, u16* __restrict__ vlb, float* __restrict__ mx)
{
  const int h = blockIdx.x;
  __shared__ __align__(16) float xin[6272];   // quantized V [p][c], stride 128
  __shared__ __align__(16) u16 Qb[64*40];     // [n][kd] int-valued bf16, stride 40
  __shared__ __align__(16) u16 Kb[64*40];     // [m][kd] int-valued bf16, stride 40
  const float sq = qsc(rdmx(mx,0), 127.f), sk = qsc(rdmx(mx,1), 127.f), sv = qsc(rdmx(mx,2), 127.f);
  const float iq = 1.f/sq, ik = 1.f/sk, iv = 1.f/sv;
  const int tid = threadIdx.x;
  const int lane = tid & 63, wid = tid >> 6;
  const int c = tid & 127, half = tid >> 7;
  float w9[9];
  #pragma unroll
  for (int t = 0; t < 9; ++t) w9[t] = wv9[h*1152 + c*9 + t];
  const float bb = bvl[h*128 + c];
  const float sscale = (sq * sk) * 0.17677669529663687f;
  const float* bx = biasx + h*2401;
  const int col = wid*16 + (lane & 15);
  float lm = 0.f, lmV = 0.f;
  for (int bb4 = 0; bb4 < 4; ++bb4){
    const int b = blockIdx.y*4 + bb4;
    __syncthreads();   // previous iteration's LDS readers done
    for (int j = tid; j < 196; j += 256){
      int n = j >> 2, d0 = (j & 3)*8;
      size_t base = (size_t)(b*49 + n)*1536;
      const bf16x8 qv = *(const bf16x8*)&qkv[base + h*32 + d0];
      const bf16x8 kv = *(const bf16x8*)&qkv[base + 256 + h*32 + d0];
      bf16x8 qo, ko;
      #pragma unroll
      for (int u = 0; u < 8; ++u){
        qo[u] = (short)f2bf(fminf(fmaxf(rintf(bf2f((u16)qv[u]) * iq), -127.f), 127.f));
        ko[u] = (short)f2bf(fminf(fmaxf(rintf(bf2f((u16)kv[u]) * ik), -127.f), 127.f));
      }
      *(bf16x8*)&Qb[n*40 + d0] = qo;
      *(bf16x8*)&Kb[n*40 + d0] = ko;
    }
    for (int j = tid; j < 784; j += 256){
      int p = j >> 4, dg = j & 15;
      const bf16x8 vv = *(const bf16x8*)&qkv[(size_t)(b*49 + p)*1536 + 512 + h*128 + dg*8];
      #pragma unroll
      for (int u = 0; u < 8; ++u)
        xin[p*128 + dg*8 + u] = fqi(bf2f((u16)vv[u]), sv, iv);
    }
    __syncthreads();
    // vl local branch: absmax + store pre-quant bf16
    {
      const int p0 = half*25, p1 = half ? 49 : 25;
      for (int p = p0; p < p1; ++p){
        const int py = p / 7, px = p - py*7;
        float acc = bb;
        #pragma unroll
        for (int dy = 0; dy < 3; ++dy){
          const int yy = py + dy - 1;
          if (yy < 0 || yy > 6) continue;
          #pragma unroll
          for (int dx = 0; dx < 3; ++dx){
            const int xx = px + dx - 1;
            if (xx < 0 || xx > 6) continue;
            acc += xin[(yy*7 + xx)*128 + c] * w9[dy*3 + dx];
          }
        }
        lmV = fmaxf(lmV, fabsf(acc));
        vlb[(size_t)(b*49 + p)*1024 + h*128 + c] = f2bf(acc);
      }
    }
    // MFMA: S(64x64) = Q(64x32) K^T(32x64)
    f32x4 acc[4] = {};
    {
      const bf16x8 bfr = *(const bf16x8*)&Kb[(wid*16 + (lane & 15))*40 + (lane >> 4)*8];
      #pragma unroll
      for (int i = 0; i < 4; ++i){
        const bf16x8 af = *(const bf16x8*)&Qb[(i*16 + (lane & 15))*40 + (lane >> 4)*8];
        acc[i] = __builtin_amdgcn_mfma_f32_16x16x32_bf16(af, bfr, acc[i], 0, 0, 0);
      }
    }
    if (col < 49){
      const size_t so = ((size_t)b*8 + h)*2401;
      #pragma unroll
      for (int i = 0; i < 4; ++i){
        #pragma unroll
        for (int q = 0; q < 4; ++q){
          const int row = i*16 + ((lane >> 4) << 2) + q;
          if (row < 49){
            float v = acc[i][q] * sscale + bx[row*49 + col];
            S[so + row*49 + col] = f2bf(v);
            lm = fmaxf(lm, fabsf(v));
          }
        }
      }
    }
  }
  blockMax2To(mx, 4, lm, 3, lmV);
}

// ---------------- talking head 1 (bf16, IN-PLACE on S; no restrict!) ----------------
__global__ __launch_bounds__(256) void th1k(
    const u16* S, const float* w1, const float* b1, u16* T, float* mx)
{
  const int b = blockIdx.y;
  const int j = blockIdx.x*256 + threadIdx.x;
  __shared__ float wsh[64];
  __shared__ float bsh[8];
  if (threadIdx.x < 64) wsh[threadIdx.x] = w1[threadIdx.x];
  if (threadIdx.x < 8)  bsh[threadIdx.x] = b1[threadIdx.x];
  __syncthreads();
  float lm = 0.f;
  if (j < 2401){
    const float s1 = qsc(rdmx(mx,4), 127.f);
    const float i1 = 1.f/s1;
    float a[8];
    #pragma unroll
    for (int h = 0; h < 8; ++h) a[h] = fqi(bf2f(S[((size_t)b*8 + h)*2401 + j]), s1, i1);
    float o8[8];
    #pragma unroll
    for (int o = 0; o < 8; ++o){
      float t = bsh[o];
      #pragma unroll
      for (int h = 0; h < 8; ++h) t += wsh[o*8 + h] * a[h];
      o8[o] = t;
      lm = fmaxf(lm, fabsf(t));
    }
    #pragma unroll
    for (int o = 0; o < 8; ++o) T[((size_t)b*8 + o)*2401 + j] = f2bf(o8[o]);
  }
  blockMaxTo(mx, 5, lm);
}

// ---------------- int softmax (I-BERT) + talking head 2 (bf16, IN-PLACE) --------------
__global__ __launch_bounds__(256) void smth2(
    const u16* T, const float* w2, const float* b2, u16* U, float* mx)
{
  const int b = blockIdx.x;
  __shared__ u16 P[19208];          // bf16 tile -> 4 blocks/CU
  __shared__ float wsh[64];
  __shared__ float bsh[8];
  const float sa = qsc(rdmx(mx,5), 127.f), ia = 1.f/sa;
  const int tid = threadIdx.x;
  if (tid < 64) wsh[tid] = w2[tid];
  if (tid < 8)  bsh[tid] = b2[tid];
  for (int j = tid; j < 19208; j += 256){
    float k = fminf(fmaxf(rintf(bf2f(T[(size_t)b*19208 + j]) * ia), -127.f), 127.f);
    P[j] = f2bf(k);                 // ints <=127: exact in bf16
  }
  __syncthreads();
  const float x0 = floorf(-0.6931f / sa);
  const float ix0 = 1.f / x0;
  const float bi = floorf((0.96963238f / 0.35815147f) / sa);
  const float ci = floorf((1.0f / 0.35815147f) / (sa * sa));
  const float Kc = ((0.35815147f * sa) * sa) * (1.f/1073741824.f);
  const float maxv = (ci * 1073741824.f) * Kc;    // analytic exp-tensor max
  const float se = fmaxf(maxv / 32767.f, 1e-8f);
  const float ise = 1.f / se;
  const float clampLo = 30.f * x0;
  for (int r = tid; r < 392; r += 256){
    u16* pr = &P[r*49];
    float rmax = -1e30f;
    for (int m = 0; m < 49; ++m) rmax = fmaxf(rmax, bf2f(pr[m]));
    float rsum = 0.f;
    for (int m = 0; m < 49; ++m){
      float xi = bf2f(pr[m]) - rmax;
      xi = fmaxf(xi, clampLo);
      float qd = floorf(xi * ix0);
      float rr = xi - x0*qd;
      float z = (rr + bi)*rr + ci;
      float ei = fmaxf(floorf(z * exp2f(30.f - qd)), 0.f);
      float e2 = fminf(fmaxf(rintf((ei * Kc) * ise), -32767.f), 32767.f);
      u16 eb = f2bf(e2);
      pr[m] = eb;
      rsum += bf2f(eb);
    }
    const float factor = floorf(4294967296.f / rsum);
    for (int m = 0; m < 49; ++m){
      float p = floorf((bf2f(pr[m]) * factor) * (1.f/65536.f)) * (1.f/65536.f);
      pr[m] = f2bf(p);
    }
  }
  __syncthreads();
  float lm = 0.f;
  for (int j = tid; j < 19208; j += 256){
    int o = j / 2401, rem = j - o*2401;
    float t = bsh[o];
    #pragma unroll
    for (int h = 0; h < 8; ++h) t += wsh[o*8 + h] * bf2f(P[h*2401 + rem]);
    U[(size_t)b*19208 + j] = f2bf(t);
    lm = fmaxf(lm, fabsf(t));
  }
  blockMaxTo(mx, 6, lm);
}

// ------ out = attn_q @ v_q + fq(vl) — MFMA; vl prefetched into REGISTERS ------------
__global__ __launch_bounds__(256) void attn_v(
    const u16* __restrict__ qkv, const u16* __restrict__ U,
    u16* __restrict__ av, float* __restrict__ mx)
{
  const int h = blockIdx.x, b = blockIdx.y;
  __shared__ __align__(16) u16 Pb[64*68];     // [n][k=m] int-valued bf16, stride 68
  __shared__ __align__(16) u16 Vt[128*66];    // [d][k=m] int-valued bf16, stride 66
  const float s3 = qsc(rdmx(mx,6), 127.f), sv = qsc(rdmx(mx,2), 127.f), svl = qsc(rdmx(mx,3), 127.f);
  const float i3 = 1.f/s3, iv = 1.f/sv, il = 1.f/svl;
  const float s3sv = s3 * sv;
  const int tid = threadIdx.x;
  const int lane = tid & 63, wid = tid >> 6;
  const int col0 = wid * 32;
  const int ca = col0 + (lane & 15), cb = ca + 16;   // the two columns this thread owns
  // prefetch vl (written by attn_qk into av) into registers, issued FIRST so the
  // HBM latency hides under P/V staging; consumed only in the epilogue.
  u16 vlrA[16], vlrB[16];
  {
    const size_t vbase = (size_t)(b*49)*1024 + h*128;
    #pragma unroll
    for (int i = 0; i < 4; ++i){
      #pragma unroll
      for (int q = 0; q < 4; ++q){
        const int row = i*16 + ((lane >> 4) << 2) + q;
        const int rr = (row < 49) ? row : 48;   // clamp (values unused for row>=49)
        vlrA[i*4+q] = av[vbase + (size_t)rr*1024 + ca];
        vlrB[i*4+q] = av[vbase + (size_t)rr*1024 + cb];
      }
    }
  }
  // zero k-pad columns only; rows >=49 of the MFMA output are discarded
  for (int j = tid; j < 64*19; j += 256){ int n = j/19, m = 49 + (j - n*19); Pb[n*68 + m] = 0; }
  for (int j = tid; j < 128*17; j += 256){ int d = j/17, m = 49 + (j - d*17); Vt[d*66 + m] = 0; }
  // P-quant: integer-valued bf16
  for (int j = tid; j < 2401; j += 256){
    int n = j / 49, m = j - n*49;
    float k = fminf(fmaxf(rintf(bf2f(U[((size_t)b*8 + h)*2401 + j]) * i3), -127.f), 127.f);
    Pb[n*68 + m] = f2bf(k);
  }
  // V-quant, d-major
  {
    const int dp = lane * 2, mc = wid;
    const int mend = (mc == 3) ? 49 : (mc*13 + 13);
    const size_t base = (size_t)(b*49)*1536 + 512 + h*128 + dp;
    for (int m = mc*13; m < mend; ++m){
      u32 two = *(const u32*)&qkv[base + (size_t)m*1536];
      float k0 = fminf(fmaxf(rintf(bf2f((u16)(two & 0xffffu)) * iv), -127.f), 127.f);
      float k1 = fminf(fmaxf(rintf(bf2f((u16)(two >> 16)) * iv), -127.f), 127.f);
      Vt[dp*66 + m]       = f2bf(k0);
      Vt[(dp + 1)*66 + m] = f2bf(k1);
    }
  }
  __syncthreads();
  // MFMA: P(64x64) x V^T(64x128) — per wave 64 rows x 32 cols
  f32x4 acc[4][2] = {};
  #pragma unroll
  for (int kk = 0; kk < 2; ++kk){
    bf16x8 af[4], bfr[2];
    #pragma unroll
    for (int i = 0; i < 4; ++i)
      af[i] = *(const bf16x8*)&Pb[(i*16 + (lane & 15))*68 + kk*32 + (lane >> 4)*8];
    #pragma unroll
    for (int j = 0; j < 2; ++j)
      bfr[j] = *(const bf16x8*)&Vt[(col0 + j*16 + (lane & 15))*66 + kk*32 + (lane >> 4)*8];
    #pragma unroll
    for (int i = 0; i < 4; ++i)
      #pragma unroll
      for (int j = 0; j < 2; ++j)
        acc[i][j] = __builtin_amdgcn_mfma_f32_16x16x32_bf16(af[i], bfr[j], acc[i][j], 0, 0, 0);
  }
  // epilogue: vl from registers, quantize, add, write
  float lm = 0.f, lmp = 0.f;
  #pragma unroll
  for (int i = 0; i < 4; ++i){
    #pragma unroll
    for (int q = 0; q < 4; ++q){
      const int row = i*16 + ((lane >> 4) << 2) + q;
      if (row < 49){
        const size_t base = (size_t)(b*49 + row)*1024 + h*128;
        const float vlA = fqi(bf2f(vlrA[i*4+q]), svl, il);
        const float vlB = fqi(bf2f(vlrB[i*4+q]), svl, il);
        const float vA = acc[i][0][q] * s3sv + vlA;
        const float vB = acc[i][1][q] * s3sv + vlB;
        av[base + ca] = f2bf(vA);
        av[base + cb] = f2bf(vB);
        lm = fmaxf(lm, fmaxf(fabsf(vA), fabsf(vB)));
        lmp = fmaxf(lmp, fmaxf(vA, vB));
      }
    }
  }
  blockMax2To(mx, 7, lm, 8, lmp);
}

// ---------------- y1 = x + ls1*quant(proj), absmax ----------------
__global__ __launch_bounds__(256) void res1max(
    const float* __restrict__ x, const u16* __restrict__ praw,
    const float* __restrict__ ls1, float* __restrict__ y1, float* __restrict__ mx)
{
  const int b = blockIdx.x;
  __shared__ float xs[18816];
  __shared__ float lss[384];
  const float sp = qsc(rdmx(mx,9), 127.f);
  const float ip = 1.f / sp;
  const int tid = threadIdx.x;
  for (int jj = tid; jj < 4704; jj += 256)
    *(float4*)&xs[jj*4] = *(const float4*)&x[(size_t)b*18816 + jj*4];
  for (int j = tid; j < 384; j += 256) lss[j] = ls1[j];
  __syncthreads();
  float lm = 0.f;
  for (int jj = tid; jj < 4704; jj += 256){
    int j = jj*4, p = j / 384, c = j - p*384;
    s16x4 pv = *(const s16x4*)&praw[(size_t)b*18816 + j];
    float4 yv;
    #pragma unroll
    for (int u = 0; u < 4; ++u){
      float y = xs[(c+u)*49 + p] + lss[c+u] * fqi(bf2f((u16)pv[u]), sp, ip);
      ((float*)&yv)[u] = y;
      lm = fmaxf(lm, fabsf(y));
    }
    *(float4*)&y1[(size_t)b*18816 + j] = yv;
  }
  blockMaxTo(mx, 10, lm);
}

// ---------------- x1 = quant(y1): bf16 only (values are 255-level quantized) ----------
__global__ void qx1(const float* __restrict__ y1, u16* __restrict__ x1b,
                    const float* __restrict__ mx){
  const float s = qsc(rdmx(mx,10), 127.f);
  const size_t n4 = (size_t)9633792/4;
  for (size_t i = (size_t)blockIdx.x*blockDim.x + threadIdx.x; i < n4; i += (size_t)gridDim.x*blockDim.x){
    float4 v = *(const float4*)(y1 + i*4);
    s16x4 ob;
    #pragma unroll
    for (int u = 0; u < 4; ++u){
      float q = fq(((const float*)&v)[u], s);   // spine: exact division
      ob[u] = (short)f2bf(q);
    }
    *(s16x4*)(x1b + i*4) = ob;
  }
}

// ---------------- depthwise 3x3 (mid conv) + relu (IN-PLACE on h1) ----------------
__global__ __launch_bounds__(128) void dw_mid(
    const u16* h1, const float* wm9, const float* bmid, u16* m1, float* mx)
{
  const int cc = blockIdx.x, b = blockIdx.y;
  __shared__ float xin[49*132];
  const float sh = qsc(rdmx(mx,11), 127.f);
  const float ih = 1.f / sh;
  const int tid = threadIdx.x;
  for (int j = tid; j < 784; j += 128){
    int p = j >> 4, dg = j & 15;
    const bf16x8 vv = *(const bf16x8*)&h1[(size_t)(b*49 + p)*1536 + cc*128 + dg*8];
    #pragma unroll
    for (int u = 0; u < 8; ++u)
      xin[p*132 + dg*8 + u] = fqi(bf2f((u16)vv[u]), sh, ih);
  }
  __syncthreads();
  const int c = tid;
  float w9[9];
  #pragma unroll
  for (int i = 0; i < 9; ++i) w9[i] = wm9[(cc*128 + c)*9 + i];
  const float bb = bmid[cc*128 + c];
  float col[49];
  #pragma unroll
  for (int p = 0; p < 49; ++p) col[p] = xin[p*132 + c];
  float lm = 0.f;
  #pragma unroll
  for (int p = 0; p < 49; ++p){
    const int py = p / 7, px = p % 7;
    float acc = bb;
    #pragma unroll
    for (int dy = 0; dy < 3; ++dy){
      const int yy = py + dy - 1;
      if (yy < 0 || yy > 6) continue;
      #pragma unroll
      for (int dx = 0; dx < 3; ++dx){
        const int xx = px + dx - 1;
        if (xx < 0 || xx > 6) continue;
        acc += col[yy*7 + xx] * w9[dy*3 + dx];
      }
    }
    acc = fmaxf(acc, 0.f);
    m1[(size_t)(b*49 + p)*1536 + cc*128 + c] = f2bf(acc);
    lm = fmaxf(lm, acc);
  }
  blockMaxTo(mx, 12, lm);
}

// ---------------- y2 = x1 + ls2*quant(fc2), absmax (bf16 in/out, x8) ----------------
__global__ __launch_bounds__(256) void res2max(
    const u16* __restrict__ x1b, const u16* __restrict__ f2,
    const float* __restrict__ ls2, u16* __restrict__ y2b, float* __restrict__ mx)
{
  const float s = qsc(rdmx(mx,13), 127.f);
  const float is = 1.f / s;
  float lm = 0.f;
  const size_t n8 = (size_t)9633792/8;
  for (size_t i = (size_t)blockIdx.x*blockDim.x + threadIdx.x; i < n8; i += (size_t)gridDim.x*blockDim.x){
    int c0 = (int)((i*8) % 384);
    bf16x8 xv = *(const bf16x8*)(x1b + i*8);
    bf16x8 fv = *(const bf16x8*)(f2 + i*8);
    bf16x8 yv;
    #pragma unroll
    for (int u = 0; u < 8; ++u){
      float y = bf2f((u16)xv[u]) + ls2[c0+u] * fqi(bf2f((u16)fv[u]), s, is);
      yv[u] = (short)f2bf(y);
      lm = fmaxf(lm, fabsf(y));
    }
    *(bf16x8*)(y2b + i*8) = yv;
  }
  blockMaxTo(mx, 14, lm);
}

// ---------------- out2 = quant(y2), transpose to NCHW, plus out_sf ----------------
__global__ __launch_bounds__(256) void finalout(
    const u16* __restrict__ y2b, float* __restrict__ out, const float* __restrict__ mx)
{
  const int b = blockIdx.x;
  __shared__ float os[18816];
  const float s = qsc(rdmx(mx,14), 127.f);
  const int tid = threadIdx.x;
  for (int jj = tid; jj < 4704; jj += 256){
    int j = jj*4, p = j / 384, c = j - p*384;
    s16x4 yv = *(const s16x4*)&y2b[(size_t)b*18816 + j];
    #pragma unroll
    for (int u = 0; u < 4; ++u)
      os[(c+u)*49 + p] = fq(bf2f((u16)yv[u]), s);   // spine: exact division
  }
  __syncthreads();
  for (int jj = tid; jj < 4704; jj += 256)
    *(float4*)&out[(size_t)b*18816 + jj*4] = *(const float4*)&os[jj*4];
  if (b == 0 && tid == 0) out[9633792] = s;
}

extern "C" void kernel_launch(void* const* d_in, const int* in_sizes, int n_in,
                              void* d_out, int out_size, void* d_ws, size_t ws_size,
                              hipStream_t stream)
{
  (void)in_sizes; (void)n_in; (void)out_size; (void)ws_size;
  const float* x    = (const float*)d_in[0];
  const float* wq   = (const float*)d_in[2];
  const float* bq   = (const float*)d_in[3];
  const float* wk   = (const float*)d_in[4];
  const float* bk   = (const float*)d_in[5];
  const float* wv   = (const float*)d_in[6];
  const float* bv   = (const float*)d_in[7];
  const float* wvl  = (const float*)d_in[8];
  const float* bvl  = (const float*)d_in[9];
  const float* ab   = (const float*)d_in[10];
  const float* wth1 = (const float*)d_in[11];
  const float* bth1 = (const float*)d_in[12];
  const float* wth2 = (const float*)d_in[13];
  const float* bth2 = (const float*)d_in[14];
  const float* wproj= (const float*)d_in[15];
  const float* bproj= (const float*)d_in[16];
  const float* wfc1 = (const float*)d_in[17];
  const float* bfc1 = (const float*)d_in[18];
  const float* wmid = (const float*)d_in[19];
  const float* bmid = (const float*)d_in[20];
  const float* wfc2 = (const float*)d_in[21];
  const float* bfc2 = (const float*)d_in[22];
  const float* ls1  = (const float*)d_in[23];
  const float* ls2  = (const float*)d_in[24];
  const int*   idxs = (const int*)d_in[25];
  float* out = (float*)d_out;

  // ---- workspace layout ----
  char* w = (char*)d_ws;
  float* biasqkv = (float*)(w + 256);
  u16* wqkv_b    = (u16*)(w + 6400);
  u16* wproj_b   = (u16*)(w + 1186048);
  u16* wfc1_b    = (u16*)(w + 1972480);
  u16* wfc2_b    = (u16*)(w + 3152128);
  float* wvl_q   = (float*)(w + 4331776);
  float* wmid_q  = (float*)(w + 4368640);
  float* wth1_q  = (float*)(w + 4423936);
  float* wth2_q  = (float*)(w + 4424192);
  // W1 (19.27 MB): xT -> praw -> x1b (alive qx1..res2max)
  u16* xT    = (u16*)(w + 4424448);
  u16* praw  = xT;
  u16* x1b   = xT;
  // W2 (77.07 MB): qkv -> h1 (dw_mid in place; fc2 reads h1 with A-quant)
  u16* qkv = (u16*)(w + 23692032);
  u16* h1  = qkv;
  // W4 (51.38 MB): avb — attn_qk stores pre-quant vl here; attn_v reads+overwrites;
  // proj gemm reads with A-quant
  u16* avb = (u16*)(w + 100762368);
  // W5 (39.34 MB): Sb bf16 (th1k/smth2 in place) -> y1 (f32) -> {f2raw, y2b} (bf16)
  u16* Sb   = (u16*)(w + 152142592);
  float* y1 = (float*)(w + 152142592);
  u16* f2raw = (u16*)(w + 152142592);             // after y1 dead (qx1 done)
  u16* y2b   = (u16*)(w + 152142592 + 19267584);  // disjoint from f2raw
  // biasx (76.8 KB) in the slack after W5
  float* biasx = (float*)(w + 190677760);
  // mx table: 16 slots x 64 regs (4 KB), after biasx
  float* mx = (float*)(w + 190754816);

  zeromx<<<1, 256, 0, stream>>>(mx);
  wquant<<<6425, 128, 0, stream>>>(wq, wk, wv, wproj, wfc1, wfc2, wvl, wmid, wth1, wth2,
                                   bq, bk, bv, ab, idxs,
                                   wqkv_b, wproj_b, wfc1_b, wfc2_b,
                                   wvl_q, wmid_q, wth1_q, wth2_q, biasqkv, biasx);
  xpose<<<512, 256, 0, stream>>>(x, xT);
  gemm_bt<<<dim3(12, 196), 256, 0, stream>>>(xT, wqkv_b, biasqkv, qkv, mx, 1536, 384, 1, 0, 0);
  attn_qk<<<dim3(8, 128), 256, 0, stream>>>(qkv, biasx, wvl_q, bvl, Sb, avb, mx);
  th1k<<<dim3(10, 512), 256, 0, stream>>>(Sb, wth1_q, bth1, Sb, mx);
  smth2<<<512, 256, 0, stream>>>(Sb, wth2_q, bth2, Sb, mx);
  attn_v<<<dim3(8, 512), 256, 0, stream>>>(qkv, Sb, avb, mx);
  gemm_bt<<<dim3(3, 196), 256, 0, stream>>>(avb, wproj_b, bproj, praw, mx, 384, 1024, 0, 9, 1);
  res1max<<<512, 256, 0, stream>>>(x, praw, ls1, y1, mx);
  qx1<<<2048, 256, 0, stream>>>(y1, x1b, mx);
  gemm_bt<<<dim3(12, 196), 256, 0, stream>>>(x1b, wfc1_b, bfc1, h1, mx, 1536, 384, 2, 11, 0);
  dw_mid<<<dim3(12, 512), 128, 0, stream>>>(h1, wmid_q, bmid, h1, mx);
  gemm_bt<<<dim3(3, 196), 256, 0, stream>>>(h1, wfc2_b, bfc2, f2raw, mx, 384, 1536, 0, 13, 2);
  res2max<<<2048, 256, 0, stream>>>(x1b, f2raw, ls2, y2b, mx);
  finalout<<<512, 256, 0, stream>>>(y2b, out, mx);
}

// Round 25
// 517.037 us; speedup vs baseline: 1.0478x; 1.0202x over previous
//
#include <hip/hip_runtime.h>

typedef unsigned short u16;
typedef unsigned int u32;
typedef float f32x4 __attribute__((ext_vector_type(4)));
typedef short bf16x8 __attribute__((ext_vector_type(8)));
typedef short s16x4 __attribute__((ext_vector_type(4)));

// ---- geometry ----
// B=512, DIM=384, RES=7, N=49, NH=8, KD=32, D=128, DH=1024, NHKD=256, HID=1536
// max-scalar table: mx[16 slots][64 regs]; readers take max over slots.
// regs: 0 Mq 1 Mk 2 Mv 3 Mvl 4 Mpre_th1 5 Mattn 6 Mpostsm 7 Mres_abs 8 Mres_pos
// 9 Mproj 10 Mx1 11 Mh1(relu) 12 Mmid(relu) 13 Mfc2 14 Mfinal

__device__ __forceinline__ u16 f2bf(float f){
  u32 x = __float_as_uint(f);
  x += 0x7fffu + ((x >> 16) & 1u);
  return (u16)(x >> 16);
}
__device__ __forceinline__ float bf2f(u16 u){ return __uint_as_float(((u32)u) << 16); }
__device__ __forceinline__ float qsc(float m, float qmax){ return fmaxf(m / qmax, 1e-8f); }
// exact-division fake quant (residual spine)
__device__ __forceinline__ float fq(float x, float s){
  return fminf(fmaxf(rintf(x / s), -127.f), 127.f) * s;
}
// reciprocal-mul fake quant (ls1/ls2-insulated paths)
__device__ __forceinline__ float fqi(float x, float s, float inv){
  return fminf(fmaxf(rintf(x * inv), -127.f), 127.f) * s;
}
// read a scale reg: max over the 16 contention slots
__device__ __forceinline__ float rdmx(const float* mx, int reg){
  float m = mx[reg];
  #pragma unroll
  for (int s = 1; s < 16; ++s) m = fmaxf(m, mx[s*64 + reg]);
  return m;
}
// wave-shuffle block max -> slotted atomic (2 barriers)
__device__ __forceinline__ void blockMaxTo(float* mx, int reg, float v){
  __shared__ float red[8];
  #pragma unroll
  for (int o = 32; o > 0; o >>= 1) v = fmaxf(v, __shfl_xor(v, o, 64));
  const int wid = threadIdx.x >> 6;
  const int nw = (int)(blockDim.x + 63) >> 6;
  __syncthreads();
  if ((threadIdx.x & 63) == 0) red[wid] = v;
  __syncthreads();
  if (threadIdx.x == 0){
    float m = red[0];
    for (int i = 1; i < nw; ++i) m = fmaxf(m, red[i]);
    const int slot = (blockIdx.x + blockIdx.y*4) & 15;
    atomicMax((int*)&mx[slot*64 + reg], __float_as_int(m));
  }
}
// two maxima in one pass (one barrier pair)
__device__ __forceinline__ void blockMax2To(float* mx, int r0i, float v0, int r1i, float v1){
  __shared__ float r0[8], r1[8];
  #pragma unroll
  for (int o = 32; o > 0; o >>= 1){
    v0 = fmaxf(v0, __shfl_xor(v0, o, 64));
    v1 = fmaxf(v1, __shfl_xor(v1, o, 64));
  }
  const int wid = threadIdx.x >> 6;
  const int nw = (int)(blockDim.x + 63) >> 6;
  __syncthreads();
  if ((threadIdx.x & 63) == 0){ r0[wid] = v0; r1[wid] = v1; }
  __syncthreads();
  if (threadIdx.x == 0){
    float m0 = r0[0], m1 = r1[0];
    for (int i = 1; i < nw; ++i){ m0 = fmaxf(m0, r0[i]); m1 = fmaxf(m1, r1[i]); }
    const int slot = (blockIdx.x + blockIdx.y*4) & 15;
    atomicMax((int*)&mx[slot*64 + r0i], __float_as_int(m0));
    atomicMax((int*)&mx[slot*64 + r1i], __float_as_int(m1));
  }
}

__device__ __forceinline__ void gload16(const void* g, void* l){
  __builtin_amdgcn_global_load_lds((const __attribute__((address_space(1))) u32*)g,
                                   (__attribute__((address_space(3))) u32*)l, 16, 0, 0);
}

__global__ void zeromx(float* mx){
  for (int j = threadIdx.x; j < 1024; j += 256) mx[j] = 0.f;
}

// ---------------- weight quantization (per-output-channel) + biasx table ----------------
__global__ __launch_bounds__(128) void wquant(
    const float* wq, const float* wk, const float* wv, const float* wproj,
    const float* wfc1, const float* wfc2, const float* wvl, const float* wmid,
    const float* wth1, const float* wth2,
    const float* bq, const float* bk, const float* bv,
    const float* ab, const int* idxs,
    u16* wqkv_b, u16* wproj_b, u16* wfc1_b, u16* wfc2_b,
    float* wvl_q, float* wmid_q, float* wth1_q, float* wth2_q, float* biasqkv,
    float* biasx)
{
  const int tid = threadIdx.x;
  const int bid = blockIdx.x;
  if (bid == 6416){
    for (int j = tid; j < 1536; j += 128){
      float v = (j < 256) ? bq[j] : ((j < 512) ? bk[j - 256] : bv[j - 512]);
      biasqkv[j] = v;
    }
    return;
  }
  if (bid >= 6417){   // relative-position bias expanded per head: biasx[h][t]
    const int h = bid - 6417;
    for (int j = tid; j < 2401; j += 128)
      biasx[h*2401 + j] = ab[h*49 + idxs[j]];
    return;
  }
  const int rows[10] = {256,256,1024,384,1536,384,1024,1536,8,8};
  int seg = 0, r = bid;
  while (r >= rows[seg]) { r -= rows[seg]; ++seg; }
  int len = 0;
  const float* src = nullptr; u16* db = nullptr; float* df = nullptr;
  switch (seg){
    case 0: len = 384;  src = wq    + r*384;  db = wqkv_b + r*384;        break;
    case 1: len = 384;  src = wk    + r*384;  db = wqkv_b + (256+r)*384;  break;
    case 2: len = 384;  src = wv    + r*384;  db = wqkv_b + (512+r)*384;  break;
    case 3: len = 1024; src = wproj + r*1024; db = wproj_b + r*1024;      break;
    case 4: len = 384;  src = wfc1  + r*384;  db = wfc1_b + r*384;        break;
    case 5: len = 1536; src = wfc2  + r*1536; db = wfc2_b + r*1536;       break;
    case 6: len = 9;    src = wvl   + r*9;    df = wvl_q + r*9;           break;
    case 7: len = 9;    src = wmid  + r*9;    df = wmid_q + r*9;          break;
    case 8: len = 8;    src = wth1  + r*8;    df = wth1_q + r*8;          break;
    default: len = 8;   src = wth2  + r*8;    df = wth2_q + r*8;          break;
  }
  float lm = 0.f;
  for (int j = tid; j < len; j += 128) lm = fmaxf(lm, fabsf(src[j]));
  __shared__ float red[128];
  red[tid] = lm; __syncthreads();
  for (int s = 64; s > 0; s >>= 1){
    if (tid < s) red[tid] = fmaxf(red[tid], red[tid + s]);
    __syncthreads();
  }
  float s = fmaxf(red[0] / 127.f, 1e-8f);
  for (int j = tid; j < len; j += 128){
    float v = fminf(fmaxf(rintf(src[j] / s), -127.f), 127.f) * s;
    if (db) db[j] = f2bf(v); else df[j] = v;
  }
}

// ---------------- x (NCHW) -> xT [m=b*49+p][c] bf16 ----------------
__global__ __launch_bounds__(256) void xpose(const float* __restrict__ x, u16* __restrict__ xT){
  const int b = blockIdx.x;
  __shared__ u16 xb[18816];
  const int tid = threadIdx.x;
  for (int jj = tid; jj < 4704; jj += 256){
    const float4 v = *(const float4*)&x[(size_t)b*18816 + jj*4];
    xb[jj*4+0] = f2bf(v.x); xb[jj*4+1] = f2bf(v.y);
    xb[jj*4+2] = f2bf(v.z); xb[jj*4+3] = f2bf(v.w);
  }
  __syncthreads();
  for (int jj = tid; jj < 4704; jj += 256){
    int j = jj*4, p = j / 384, c = j - p*384;
    s16x4 o;
    #pragma unroll
    for (int u = 0; u < 4; ++u) o[u] = (short)xb[(c+u)*49 + p];
    *(s16x4*)&xT[(size_t)b*18816 + j] = o;
  }
}

// ---------------- bf16 MFMA GEMM: C[M][N] = A[M][K] * Bt[N][K]^T + bias ----------------
// R16/R18 known-good structure + __launch_bounds__(256,3). SESSION-FINAL GEMM:
// T1 XCD-bijective remap + T2 st-16 XOR swizzle (conflicts=0), single-buffer
// 2-barrier loop (33 KB LDS, 64 VGPR). Escape attempts all measured dead ends:
// R17 dbuf (LDS x2 -> occupancy cliff), R19 BM=256 (VGPR cliff), R23 BK=32
// counted-vmcnt (neutral — cross-block overlap already hides the drain).
__global__ __launch_bounds__(256, 3) void gemm_bt(
    const u16* __restrict__ A, const u16* __restrict__ Bt,
    const float* __restrict__ bias, u16* __restrict__ C,
    float* __restrict__ mx, int N, int K, int epi, int region, int aquant)
{
  const int nx = gridDim.x;
  const int nwg = nx * gridDim.y;
  const int orig = blockIdx.x + nx * blockIdx.y;      // HW dispatch order (x fastest)
  const int q8 = nwg >> 3, r8 = nwg & 7;
  const int xcd = orig & 7;
  const int lid = ((xcd < r8) ? xcd*(q8+1) : r8*(q8+1) + (xcd - r8)*q8) + (orig >> 3);
  const int n0 = (lid % nx) * 128;
  const int m0 = (lid / nx) * 128;
  __shared__ __align__(16) u16 As[128*64];
  __shared__ __align__(16) u16 Bs[128*64];
  const int tid = threadIdx.x;
  const int lane = tid & 63, wid = tid >> 6;
  const int wr = wid >> 1, wc = wid & 1;
  float qa_s0 = 1.f, qa_i0 = 1.f, qa_s1 = 1.f, qa_i1 = 1.f;
  if (aquant == 1){
    qa_s0 = qsc(rdmx(mx,7), 127.f); qa_i0 = 1.f/qa_s0;
    float posq = fq(rdmx(mx,8), qa_s0);
    qa_s1 = fmaxf(posq / 127.f, 1e-8f); qa_i1 = 1.f/qa_s1;
  } else if (aquant == 2){
    qa_s0 = qsc(rdmx(mx,12), 127.f); qa_i0 = 1.f/qa_s0;
  }
  f32x4 acc[4][4] = {};
  const int nsteps = K >> 6;
  for (int s = 0; s < nsteps; ++s){
    const int k0 = s << 6;
    #pragma unroll
    for (int j = 0; j < 4; ++j){
      int boff = j*4096 + tid*16;      // LDS byte offset (wave-linear dest)
      int row = boff >> 7;
      // inverse-swizzled global source column (involution: read applies same XOR)
      int ce  = (((boff & 127) ^ ((row & 7) << 4)) >> 1);
      if (aquant == 0){
        gload16(A + (size_t)(m0 + row)*K + k0 + ce, (char*)As + boff);
      } else {
        uint4 va = *(const uint4*)(A + (size_t)(m0 + row)*K + k0 + ce);
        u16* e = (u16*)&va;
        #pragma unroll
        for (int u = 0; u < 8; ++u){
          float f = bf2f(e[u]);
          if (aquant == 1){
            f = fmaxf(fqi(f, qa_s0, qa_i0), 0.f);
            f = fqi(f, qa_s1, qa_i1);
          } else {
            f = fqi(f, qa_s0, qa_i0);
          }
          e[u] = f2bf(f);
        }
        *(uint4*)((char*)As + boff) = va;
      }
      gload16(Bt + (size_t)(n0 + row)*K + k0 + ce, (char*)Bs + boff);
    }
    __syncthreads();
    #pragma unroll
    for (int kk = 0; kk < 2; ++kk){
      bf16x8 af[4], bfr[4];
      #pragma unroll
      for (int i = 0; i < 4; ++i){
        int ar = wr*64 + i*16 + (lane & 15);
        int aidx = (ar*64 + kk*32 + (lane >> 4)*8) ^ ((ar & 7) << 3);
        af[i]  = *(const bf16x8*)&As[aidx];
        int br = wc*64 + i*16 + (lane & 15);
        int bidx = (br*64 + kk*32 + (lane >> 4)*8) ^ ((br & 7) << 3);
        bfr[i] = *(const bf16x8*)&Bs[bidx];
      }
      #pragma unroll
      for (int i = 0; i < 4; ++i){
        #pragma unroll
        for (int j = 0; j < 4; ++j){
          acc[i][j] = __builtin_amdgcn_mfma_f32_16x16x32_bf16(af[i], bfr[j], acc[i][j], 0, 0, 0);
        }
      }
    }
    __syncthreads();
  }
  float lm = 0.f;
  #pragma unroll
  for (int i = 0; i < 4; ++i){
    int rbase = m0 + wr*64 + i*16 + ((lane >> 4) << 2);
    #pragma unroll
    for (int j = 0; j < 4; ++j){
      int col = n0 + wc*64 + j*16 + (lane & 15);
      float bv = bias[col];
      #pragma unroll
      for (int q = 0; q < 4; ++q){
        float v = acc[i][j][q] + bv;
        if (epi == 2) v = fmaxf(v, 0.f);
        C[(size_t)(rbase + q)*N + col] = f2bf(v);
        lm = fmaxf(lm, (epi == 2) ? v : fabsf(v));
      }
    }
  }
  int reg = region;
  if (epi == 1) reg = (n0 < 256) ? 0 : ((n0 < 512) ? 1 : 2);
  blockMaxTo(mx, reg, lm);
}

// ---------------- S = q*k^T*scale + bias — MFMA, 4 batches/block ----------------
__global__ __launch_bounds__(256) void attn_qk(
    const u16* __restrict__ qkv, const float* __restrict__ biasx,
    const float* __restrict__ wv9, const float* __restrict__ bvl,
    u16* __restrict__ S, u16* __restrict__ vlb, float* __restrict__ mx)
{
  const int h = blockIdx.x;
  __shared__ __align__(16) float xin[6272];   // quantized V [p][c], stride 128
  __shared__ __align__(16) u16 Qb[64*40];     // [n][kd] int-valued bf16, stride 40
  __shared__ __align__(16) u16 Kb[64*40];     // [m][kd] int-valued bf16, stride 40
  const float sq = qsc(rdmx(mx,0), 127.f), sk = qsc(rdmx(mx,1), 127.f), sv = qsc(rdmx(mx,2), 127.f);
  const float iq = 1.f/sq, ik = 1.f/sk, iv = 1.f/sv;
  const int tid = threadIdx.x;
  const int lane = tid & 63, wid = tid >> 6;
  const int c = tid & 127, half = tid >> 7;
  float w9[9];
  #pragma unroll
  for (int t = 0; t < 9; ++t) w9[t] = wv9[h*1152 + c*9 + t];
  const float bb = bvl[h*128 + c];
  const float sscale = (sq * sk) * 0.17677669529663687f;
  const float* bx = biasx + h*2401;
  const int col = wid*16 + (lane & 15);
  float lm = 0.f, lmV = 0.f;
  for (int bb4 = 0; bb4 < 4; ++bb4){
    const int b = blockIdx.y*4 + bb4;
    __syncthreads();   // previous iteration's LDS readers done
    for (int j = tid; j < 196; j += 256){
      int n = j >> 2, d0 = (j & 3)*8;
      size_t base = (size_t)(b*49 + n)*1536;
      const bf16x8 qv = *(const bf16x8*)&qkv[base + h*32 + d0];
      const bf16x8 kv = *(const bf16x8*)&qkv[base + 256 + h*32 + d0];
      bf16x8 qo, ko;
      #pragma unroll
      for (int u = 0; u < 8; ++u){
        qo[u] = (short)f2bf(fminf(fmaxf(rintf(bf2f((u16)qv[u]) * iq), -127.f), 127.f));
        ko[u] = (short)f2bf(fminf(fmaxf(rintf(bf2f((u16)kv[u]) * ik), -127.f), 127.f));
      }
      *(bf16x8*)&Qb[n*40 + d0] = qo;
      *(bf16x8*)&Kb[n*40 + d0] = ko;
    }
    for (int j = tid; j < 784; j += 256){
      int p = j >> 4, dg = j & 15;
      const bf16x8 vv = *(const bf16x8*)&qkv[(size_t)(b*49 + p)*1536 + 512 + h*128 + dg*8];
      #pragma unroll
      for (int u = 0; u < 8; ++u)
        xin[p*128 + dg*8 + u] = fqi(bf2f((u16)vv[u]), sv, iv);
    }
    __syncthreads();
    // vl local branch: absmax + store pre-quant bf16
    {
      const int p0 = half*25, p1 = half ? 49 : 25;
      for (int p = p0; p < p1; ++p){
        const int py = p / 7, px = p - py*7;
        float acc = bb;
        #pragma unroll
        for (int dy = 0; dy < 3; ++dy){
          const int yy = py + dy - 1;
          if (yy < 0 || yy > 6) continue;
          #pragma unroll
          for (int dx = 0; dx < 3; ++dx){
            const int xx = px + dx - 1;
            if (xx < 0 || xx > 6) continue;
            acc += xin[(yy*7 + xx)*128 + c] * w9[dy*3 + dx];
          }
        }
        lmV = fmaxf(lmV, fabsf(acc));
        vlb[(size_t)(b*49 + p)*1024 + h*128 + c] = f2bf(acc);
      }
    }
    // MFMA: S(64x64) = Q(64x32) K^T(32x64)
    f32x4 acc[4] = {};
    {
      const bf16x8 bfr = *(const bf16x8*)&Kb[(wid*16 + (lane & 15))*40 + (lane >> 4)*8];
      #pragma unroll
      for (int i = 0; i < 4; ++i){
        const bf16x8 af = *(const bf16x8*)&Qb[(i*16 + (lane & 15))*40 + (lane >> 4)*8];
        acc[i] = __builtin_amdgcn_mfma_f32_16x16x32_bf16(af, bfr, acc[i], 0, 0, 0);
      }
    }
    if (col < 49){
      const size_t so = ((size_t)b*8 + h)*2401;
      #pragma unroll
      for (int i = 0; i < 4; ++i){
        #pragma unroll
        for (int q = 0; q < 4; ++q){
          const int row = i*16 + ((lane >> 4) << 2) + q;
          if (row < 49){
            float v = acc[i][q] * sscale + bx[row*49 + col];
            S[so + row*49 + col] = f2bf(v);
            lm = fmaxf(lm, fabsf(v));
          }
        }
      }
    }
  }
  blockMax2To(mx, 4, lm, 3, lmV);
}

// ---------------- talking head 1 (bf16, IN-PLACE on S; no restrict!) ----------------
__global__ __launch_bounds__(256) void th1k(
    const u16* S, const float* w1, const float* b1, u16* T, float* mx)
{
  const int b = blockIdx.y;
  const int j = blockIdx.x*256 + threadIdx.x;
  __shared__ float wsh[64];
  __shared__ float bsh[8];
  if (threadIdx.x < 64) wsh[threadIdx.x] = w1[threadIdx.x];
  if (threadIdx.x < 8)  bsh[threadIdx.x] = b1[threadIdx.x];
  __syncthreads();
  float lm = 0.f;
  if (j < 2401){
    const float s1 = qsc(rdmx(mx,4), 127.f);
    const float i1 = 1.f/s1;
    float a[8];
    #pragma unroll
    for (int h = 0; h < 8; ++h) a[h] = fqi(bf2f(S[((size_t)b*8 + h)*2401 + j]), s1, i1);
    float o8[8];
    #pragma unroll
    for (int o = 0; o < 8; ++o){
      float t = bsh[o];
      #pragma unroll
      for (int h = 0; h < 8; ++h) t += wsh[o*8 + h] * a[h];
      o8[o] = t;
      lm = fmaxf(lm, fabsf(t));
    }
    #pragma unroll
    for (int o = 0; o < 8; ++o) T[((size_t)b*8 + o)*2401 + j] = f2bf(o8[o]);
  }
  blockMaxTo(mx, 5, lm);
}

// ---------------- int softmax (I-BERT) + talking head 2 (bf16, IN-PLACE) --------------
__global__ __launch_bounds__(256) void smth2(
    const u16* T, const float* w2, const float* b2, u16* U, float* mx)
{
  const int b = blockIdx.x;
  __shared__ u16 P[19208];          // bf16 tile -> 4 blocks/CU
  __shared__ float wsh[64];
  __shared__ float bsh[8];
  const float sa = qsc(rdmx(mx,5), 127.f), ia = 1.f/sa;
  const int tid = threadIdx.x;
  if (tid < 64) wsh[tid] = w2[tid];
  if (tid < 8)  bsh[tid] = b2[tid];
  for (int j = tid; j < 19208; j += 256){
    float k = fminf(fmaxf(rintf(bf2f(T[(size_t)b*19208 + j]) * ia), -127.f), 127.f);
    P[j] = f2bf(k);                 // ints <=127: exact in bf16
  }
  __syncthreads();
  const float x0 = floorf(-0.6931f / sa);
  const float ix0 = 1.f / x0;
  const float bi = floorf((0.96963238f / 0.35815147f) / sa);
  const float ci = floorf((1.0f / 0.35815147f) / (sa * sa));
  const float Kc = ((0.35815147f * sa) * sa) * (1.f/1073741824.f);
  const float maxv = (ci * 1073741824.f) * Kc;    // analytic exp-tensor max
  const float se = fmaxf(maxv / 32767.f, 1e-8f);
  const float ise = 1.f / se;
  const float clampLo = 30.f * x0;
  for (int r = tid; r < 392; r += 256){
    u16* pr = &P[r*49];
    float rmax = -1e30f;
    for (int m = 0; m < 49; ++m) rmax = fmaxf(rmax, bf2f(pr[m]));
    float rsum = 0.f;
    for (int m = 0; m < 49; ++m){
      float xi = bf2f(pr[m]) - rmax;
      xi = fmaxf(xi, clampLo);
      float qd = floorf(xi * ix0);
      float rr = xi - x0*qd;
      float z = (rr + bi)*rr + ci;
      float ei = fmaxf(floorf(z * exp2f(30.f - qd)), 0.f);
      float e2 = fminf(fmaxf(rintf((ei * Kc) * ise), -32767.f), 32767.f);
      u16 eb = f2bf(e2);
      pr[m] = eb;
      rsum += bf2f(eb);
    }
    const float factor = floorf(4294967296.f / rsum);
    for (int m = 0; m < 49; ++m){
      float p = floorf((bf2f(pr[m]) * factor) * (1.f/65536.f)) * (1.f/65536.f);
      pr[m] = f2bf(p);
    }
  }
  __syncthreads();
  float lm = 0.f;
  for (int j = tid; j < 19208; j += 256){
    int o = j / 2401, rem = j - o*2401;
    float t = bsh[o];
    #pragma unroll
    for (int h = 0; h < 8; ++h) t += wsh[o*8 + h] * bf2f(P[h*2401 + rem]);
    U[(size_t)b*19208 + j] = f2bf(t);
    lm = fmaxf(lm, fabsf(t));
  }
  blockMaxTo(mx, 6, lm);
}

// ------ out = attn_q @ v_q + fq(vl) — MFMA; vl prefetched into REGISTERS ------------
__global__ __launch_bounds__(256) void attn_v(
    const u16* __restrict__ qkv, const u16* __restrict__ U,
    u16* __restrict__ av, float* __restrict__ mx)
{
  const int h = blockIdx.x, b = blockIdx.y;
  __shared__ __align__(16) u16 Pb[64*68];     // [n][k=m] int-valued bf16, stride 68
  __shared__ __align__(16) u16 Vt[128*66];    // [d][k=m] int-valued bf16, stride 66
  const float s3 = qsc(rdmx(mx,6), 127.f), sv = qsc(rdmx(mx,2), 127.f), svl = qsc(rdmx(mx,3), 127.f);
  const float i3 = 1.f/s3, iv = 1.f/sv, il = 1.f/svl;
  const float s3sv = s3 * sv;
  const int tid = threadIdx.x;
  const int lane = tid & 63, wid = tid >> 6;
  const int col0 = wid * 32;
  const int ca = col0 + (lane & 15), cb = ca + 16;   // the two columns this thread owns
  // prefetch vl (written by attn_qk into av) into registers, issued FIRST so the
  // HBM latency hides under P/V staging; consumed only in the epilogue.
  u16 vlrA[16], vlrB[16];
  {
    const size_t vbase = (size_t)(b*49)*1024 + h*128;
    #pragma unroll
    for (int i = 0; i < 4; ++i){
      #pragma unroll
      for (int q = 0; q < 4; ++q){
        const int row = i*16 + ((lane >> 4) << 2) + q;
        const int rr = (row < 49) ? row : 48;   // clamp (values unused for row>=49)
        vlrA[i*4+q] = av[vbase + (size_t)rr*1024 + ca];
        vlrB[i*4+q] = av[vbase + (size_t)rr*1024 + cb];
      }
    }
  }
  // zero k-pad columns only; rows >=49 of the MFMA output are discarded
  for (int j = tid; j < 64*19; j += 256){ int n = j/19, m = 49 + (j - n*19); Pb[n*68 + m] = 0; }
  for (int j = tid; j < 128*17; j += 256){ int d = j/17, m = 49 + (j - d*17); Vt[d*66 + m] = 0; }
  // P-quant: integer-valued bf16
  for (int j = tid; j < 2401; j += 256){
    int n = j / 49, m = j - n*49;
    float k = fminf(fmaxf(rintf(bf2f(U[((size_t)b*8 + h)*2401 + j]) * i3), -127.f), 127.f);
    Pb[n*68 + m] = f2bf(k);
  }
  // V-quant, d-major
  {
    const int dp = lane * 2, mc = wid;
    const int mend = (mc == 3) ? 49 : (mc*13 + 13);
    const size_t base = (size_t)(b*49)*1536 + 512 + h*128 + dp;
    for (int m = mc*13; m < mend; ++m){
      u32 two = *(const u32*)&qkv[base + (size_t)m*1536];
      float k0 = fminf(fmaxf(rintf(bf2f((u16)(two & 0xffffu)) * iv), -127.f), 127.f);
      float k1 = fminf(fmaxf(rintf(bf2f((u16)(two >> 16)) * iv), -127.f), 127.f);
      Vt[dp*66 + m]       = f2bf(k0);
      Vt[(dp + 1)*66 + m] = f2bf(k1);
    }
  }
  __syncthreads();
  // MFMA: P(64x64) x V^T(64x128) — per wave 64 rows x 32 cols
  f32x4 acc[4][2] = {};
  #pragma unroll
  for (int kk = 0; kk < 2; ++kk){
    bf16x8 af[4], bfr[2];
    #pragma unroll
    for (int i = 0; i < 4; ++i)
      af[i] = *(const bf16x8*)&Pb[(i*16 + (lane & 15))*68 + kk*32 + (lane >> 4)*8];
    #pragma unroll
    for (int j = 0; j < 2; ++j)
      bfr[j] = *(const bf16x8*)&Vt[(col0 + j*16 + (lane & 15))*66 + kk*32 + (lane >> 4)*8];
    #pragma unroll
    for (int i = 0; i < 4; ++i)
      #pragma unroll
      for (int j = 0; j < 2; ++j)
        acc[i][j] = __builtin_amdgcn_mfma_f32_16x16x32_bf16(af[i], bfr[j], acc[i][j], 0, 0, 0);
  }
  // epilogue: vl from registers, quantize, add, write
  float lm = 0.f, lmp = 0.f;
  #pragma unroll
  for (int i = 0; i < 4; ++i){
    #pragma unroll
    for (int q = 0; q < 4; ++q){
      const int row = i*16 + ((lane >> 4) << 2) + q;
      if (row < 49){
        const size_t base = (size_t)(b*49 + row)*1024 + h*128;
        const float vlA = fqi(bf2f(vlrA[i*4+q]), svl, il);
        const float vlB = fqi(bf2f(vlrB[i*4+q]), svl, il);
        const float vA = acc[i][0][q] * s3sv + vlA;
        const float vB = acc[i][1][q] * s3sv + vlB;
        av[base + ca] = f2bf(vA);
        av[base + cb] = f2bf(vB);
        lm = fmaxf(lm, fmaxf(fabsf(vA), fabsf(vB)));
        lmp = fmaxf(lmp, fmaxf(vA, vB));
      }
    }
  }
  blockMax2To(mx, 7, lm, 8, lmp);
}

// ---------------- y1 = bf16(x) + ls1*quant(proj) — pure streaming bf16 x8 -------------
// R25: reads xT (bf16 [m][c], still alive) instead of re-reading x fp32 + LDS
// transpose; writes y1 as bf16. Saves ~58 MB HBM across res1max+qx1. Numerics:
// bf16(x)/bf16(y1) add <=2^-9 rel pre-quant noise -> bounded by one extra
// x1-quant step (see R21 pattern).
__global__ __launch_bounds__(256) void res1max(
    const u16* __restrict__ xT, const u16* __restrict__ praw,
    const float* __restrict__ ls1, u16* __restrict__ y1b, float* __restrict__ mx)
{
  const float sp = qsc(rdmx(mx,9), 127.f);
  const float ip = 1.f / sp;
  float lm = 0.f;
  const size_t n8 = (size_t)9633792/8;
  for (size_t i = (size_t)blockIdx.x*blockDim.x + threadIdx.x; i < n8; i += (size_t)gridDim.x*blockDim.x){
    int c0 = (int)((i*8) % 384);
    bf16x8 xv = *(const bf16x8*)(xT + i*8);
    bf16x8 pv = *(const bf16x8*)(praw + i*8);
    bf16x8 yv;
    #pragma unroll
    for (int u = 0; u < 8; ++u){
      float y = bf2f((u16)xv[u]) + ls1[c0+u] * fqi(bf2f((u16)pv[u]), sp, ip);
      yv[u] = (short)f2bf(y);
      lm = fmaxf(lm, fabsf(y));
    }
    *(bf16x8*)(y1b + i*8) = yv;
  }
  blockMaxTo(mx, 10, lm);
}

// ---------------- x1 = quant(y1): bf16 in/out ----------------
__global__ void qx1(const u16* __restrict__ y1b, u16* __restrict__ x1b,
                    const float* __restrict__ mx){
  const float s = qsc(rdmx(mx,10), 127.f);
  const size_t n8 = (size_t)9633792/8;
  for (size_t i = (size_t)blockIdx.x*blockDim.x + threadIdx.x; i < n8; i += (size_t)gridDim.x*blockDim.x){
    bf16x8 v = *(const bf16x8*)(y1b + i*8);
    bf16x8 ob;
    #pragma unroll
    for (int u = 0; u < 8; ++u){
      float q = fq(bf2f((u16)v[u]), s);   // spine: exact division
      ob[u] = (short)f2bf(q);
    }
    *(bf16x8*)(x1b + i*8) = ob;
  }
}

// ---------------- depthwise 3x3 (mid conv) + relu (IN-PLACE on h1) ----------------
__global__ __launch_bounds__(128) void dw_mid(
    const u16* h1, const float* wm9, const float* bmid, u16* m1, float* mx)
{
  const int cc = blockIdx.x, b = blockIdx.y;
  __shared__ float xin[49*132];
  const float sh = qsc(rdmx(mx,11), 127.f);
  const float ih = 1.f / sh;
  const int tid = threadIdx.x;
  for (int j = tid; j < 784; j += 128){
    int p = j >> 4, dg = j & 15;
    const bf16x8 vv = *(const bf16x8*)&h1[(size_t)(b*49 + p)*1536 + cc*128 + dg*8];
    #pragma unroll
    for (int u = 0; u < 8; ++u)
      xin[p*132 + dg*8 + u] = fqi(bf2f((u16)vv[u]), sh, ih);
  }
  __syncthreads();
  const int c = tid;
  float w9[9];
  #pragma unroll
  for (int i = 0; i < 9; ++i) w9[i] = wm9[(cc*128 + c)*9 + i];
  const float bb = bmid[cc*128 + c];
  float col[49];
  #pragma unroll
  for (int p = 0; p < 49; ++p) col[p] = xin[p*132 + c];
  float lm = 0.f;
  #pragma unroll
  for (int p = 0; p < 49; ++p){
    const int py = p / 7, px = p % 7;
    float acc = bb;
    #pragma unroll
    for (int dy = 0; dy < 3; ++dy){
      const int yy = py + dy - 1;
      if (yy < 0 || yy > 6) continue;
      #pragma unroll
      for (int dx = 0; dx < 3; ++dx){
        const int xx = px + dx - 1;
        if (xx < 0 || xx > 6) continue;
        acc += col[yy*7 + xx] * w9[dy*3 + dx];
      }
    }
    acc = fmaxf(acc, 0.f);
    m1[(size_t)(b*49 + p)*1536 + cc*128 + c] = f2bf(acc);
    lm = fmaxf(lm, acc);
  }
  blockMaxTo(mx, 12, lm);
}

// ---------------- y2 = x1 + ls2*quant(fc2), absmax (bf16 in/out, x8) ----------------
__global__ __launch_bounds__(256) void res2max(
    const u16* __restrict__ x1b, const u16* __restrict__ f2,
    const float* __restrict__ ls2, u16* __restrict__ y2b, float* __restrict__ mx)
{
  const float s = qsc(rdmx(mx,13), 127.f);
  const float is = 1.f / s;
  float lm = 0.f;
  const size_t n8 = (size_t)9633792/8;
  for (size_t i = (size_t)blockIdx.x*blockDim.x + threadIdx.x; i < n8; i += (size_t)gridDim.x*blockDim.x){
    int c0 = (int)((i*8) % 384);
    bf16x8 xv = *(const bf16x8*)(x1b + i*8);
    bf16x8 fv = *(const bf16x8*)(f2 + i*8);
    bf16x8 yv;
    #pragma unroll
    for (int u = 0; u < 8; ++u){
      float y = bf2f((u16)xv[u]) + ls2[c0+u] * fqi(bf2f((u16)fv[u]), s, is);
      yv[u] = (short)f2bf(y);
      lm = fmaxf(lm, fabsf(y));
    }
    *(bf16x8*)(y2b + i*8) = yv;
  }
  blockMaxTo(mx, 14, lm);
}

// ---------------- out2 = quant(y2), transpose to NCHW, plus out_sf ----------------
__global__ __launch_bounds__(256) void finalout(
    const u16* __restrict__ y2b, float* __restrict__ out, const float* __restrict__ mx)
{
  const int b = blockIdx.x;
  __shared__ float os[18816];
  const float s = qsc(rdmx(mx,14), 127.f);
  const int tid = threadIdx.x;
  for (int jj = tid; jj < 4704; jj += 256){
    int j = jj*4, p = j / 384, c = j - p*384;
    s16x4 yv = *(const s16x4*)&y2b[(size_t)b*18816 + j];
    #pragma unroll
    for (int u = 0; u < 4; ++u)
      os[(c+u)*49 + p] = fq(bf2f((u16)yv[u]), s);   // spine: exact division
  }
  __syncthreads();
  for (int jj = tid; jj < 4704; jj += 256)
    *(float4*)&out[(size_t)b*18816 + jj*4] = *(const float4*)&os[jj*4];
  if (b == 0 && tid == 0) out[9633792] = s;
}

extern "C" void kernel_launch(void* const* d_in, const int* in_sizes, int n_in,
                              void* d_out, int out_size, void* d_ws, size_t ws_size,
                              hipStream_t stream)
{
  (void)in_sizes; (void)n_in; (void)out_size; (void)ws_size;
  const float* x    = (const float*)d_in[0];
  const float* wq   = (const float*)d_in[2];
  const float* bq   = (const float*)d_in[3];
  const float* wk   = (const float*)d_in[4];
  const float* bk   = (const float*)d_in[5];
  const float* wv   = (const float*)d_in[6];
  const float* bv   = (const float*)d_in[7];
  const float* wvl  = (const float*)d_in[8];
  const float* bvl  = (const float*)d_in[9];
  const float* ab   = (const float*)d_in[10];
  const float* wth1 = (const float*)d_in[11];
  const float* bth1 = (const float*)d_in[12];
  const float* wth2 = (const float*)d_in[13];
  const float* bth2 = (const float*)d_in[14];
  const float* wproj= (const float*)d_in[15];
  const float* bproj= (const float*)d_in[16];
  const float* wfc1 = (const float*)d_in[17];
  const float* bfc1 = (const float*)d_in[18];
  const float* wmid = (const float*)d_in[19];
  const float* bmid = (const float*)d_in[20];
  const float* wfc2 = (const float*)d_in[21];
  const float* bfc2 = (const float*)d_in[22];
  const float* ls1  = (const float*)d_in[23];
  const float* ls2  = (const float*)d_in[24];
  const int*   idxs = (const int*)d_in[25];
  float* out = (float*)d_out;

  // ---- workspace layout ----
  char* w = (char*)d_ws;
  float* biasqkv = (float*)(w + 256);
  u16* wqkv_b    = (u16*)(w + 6400);
  u16* wproj_b   = (u16*)(w + 1186048);
  u16* wfc1_b    = (u16*)(w + 1972480);
  u16* wfc2_b    = (u16*)(w + 3152128);
  float* wvl_q   = (float*)(w + 4331776);
  float* wmid_q  = (float*)(w + 4368640);
  float* wth1_q  = (float*)(w + 4423936);
  float* wth2_q  = (float*)(w + 4424192);
  // W1 (19.27 MB): xT (alive through res1max) -> x1b (qx1 out; fc1+res2max read)
  u16* xT    = (u16*)(w + 4424448);
  u16* x1b   = xT;
  // W2 (77.07 MB): qkv -> h1 (dw_mid in place; fc2 reads h1 with A-quant)
  u16* qkv = (u16*)(w + 23692032);
  u16* h1  = qkv;
  // W4 (51.38 MB): avb — attn_qk stores pre-quant vl here; attn_v reads+overwrites;
  // proj gemm reads with A-quant
  u16* avb = (u16*)(w + 100762368);
  // W5 (39.34 MB): Sb bf16 (th1k/smth2 in place, dead after attn_v)
  //   -> praw (W5+0) + y1b (W5+19.3MB)   [proj out / res1max out]
  //   -> f2raw (W5+0, praw dead) + y2b (W5+19.3MB, y1b dead)
  u16* Sb    = (u16*)(w + 152142592);
  u16* praw  = (u16*)(w + 152142592);
  u16* y1b   = (u16*)(w + 152142592 + 19267584);
  u16* f2raw = (u16*)(w + 152142592);
  u16* y2b   = (u16*)(w + 152142592 + 19267584);
  // biasx (76.8 KB) in the slack after W5
  float* biasx = (float*)(w + 190677760);
  // mx table: 16 slots x 64 regs (4 KB), after biasx
  float* mx = (float*)(w + 190754816);

  zeromx<<<1, 256, 0, stream>>>(mx);
  wquant<<<6425, 128, 0, stream>>>(wq, wk, wv, wproj, wfc1, wfc2, wvl, wmid, wth1, wth2,
                                   bq, bk, bv, ab, idxs,
                                   wqkv_b, wproj_b, wfc1_b, wfc2_b,
                                   wvl_q, wmid_q, wth1_q, wth2_q, biasqkv, biasx);
  xpose<<<512, 256, 0, stream>>>(x, xT);
  gemm_bt<<<dim3(12, 196), 256, 0, stream>>>(xT, wqkv_b, biasqkv, qkv, mx, 1536, 384, 1, 0, 0);
  attn_qk<<<dim3(8, 128), 256, 0, stream>>>(qkv, biasx, wvl_q, bvl, Sb, avb, mx);
  th1k<<<dim3(10, 512), 256, 0, stream>>>(Sb, wth1_q, bth1, Sb, mx);
  smth2<<<512, 256, 0, stream>>>(Sb, wth2_q, bth2, Sb, mx);
  attn_v<<<dim3(8, 512), 256, 0, stream>>>(qkv, Sb, avb, mx);
  gemm_bt<<<dim3(3, 196), 256, 0, stream>>>(avb, wproj_b, bproj, praw, mx, 384, 1024, 0, 9, 1);
  res1max<<<2048, 256, 0, stream>>>(xT, praw, ls1, y1b, mx);
  qx1<<<2048, 256, 0, stream>>>(y1b, x1b, mx);
  gemm_bt<<<dim3(12, 196), 256, 0, stream>>>(x1b, wfc1_b, bfc1, h1, mx, 1536, 384, 2, 11, 0);
  dw_mid<<<dim3(12, 512), 128, 0, stream>>>(h1, wmid_q, bmid, h1, mx);
  gemm_bt<<<dim3(3, 196), 256, 0, stream>>>(h1, wfc2_b, bfc2, f2raw, mx, 384, 1536, 0, 13, 2);
  res2max<<<2048, 256, 0, stream>>>(x1b, f2raw, ls2, y2b, mx);
  finalout<<<512, 256, 0, stream>>>(y2b, out, mx);
}